// Round 1
// baseline (951.660 us; speedup 1.0000x reference)
//
#include <hip/hip_runtime.h>
#include <hip/hip_bf16.h>
#include <stdint.h>

typedef unsigned long long u64;

#define AN 15
#define HH 200
#define WW 320
#define HWSZ (HH*WW)          // 64000
#define PER (AN*HWSZ)         // 960000 anchors per image
#define NB 8
#define K_PRE 2000
#define K_POST 1000
#define CAP 4096
#define NMS_TH 0.7f
#define BBOX_CLIP_F 4.135166556742356f   // log(1000/16)

__device__ __forceinline__ unsigned keyOf(float f) {
    unsigned u = __float_as_uint(f);
    return (u & 0x80000000u) ? ~u : (u | 0x80000000u);
}
__device__ __forceinline__ float valOf(unsigned k) {
    unsigned u = (k & 0x80000000u) ? (k ^ 0x80000000u) : ~k;
    return __uint_as_float(u);
}

// ---------------- pass 1: 256-bin histogram of key top byte, per image -----
__global__ void k_hist1(const float* __restrict__ cls, unsigned* __restrict__ hist) {
    int n = blockIdx.y;
    const float* p = cls + (size_t)n * PER;
    __shared__ unsigned lh[256];
    lh[threadIdx.x] = 0;
    __syncthreads();
    int stride = gridDim.x * blockDim.x;
    for (int i = blockIdx.x * blockDim.x + threadIdx.x; i < PER; i += stride) {
        unsigned key = keyOf(p[i]);
        atomicAdd(&lh[key >> 24], 1u);
    }
    __syncthreads();
    if (lh[threadIdx.x]) atomicAdd(&hist[n * 256 + threadIdx.x], lh[threadIdx.x]);
}

// find top-byte threshold bin: smallest b (scanning from 255 down) with cum>=K_PRE
__global__ void k_sel1(const unsigned* __restrict__ hist,
                       unsigned* __restrict__ selB1, unsigned* __restrict__ selAbove) {
    int n = threadIdx.x;
    if (n >= NB) return;
    unsigned cum = 0; int b = 0;
    for (b = 255; b >= 0; --b) {
        unsigned c = hist[n * 256 + b];
        if (cum + c >= K_PRE) break;
        cum += c;
    }
    if (b < 0) b = 0;
    selB1[n] = (unsigned)b;
    selAbove[n] = cum;          // count strictly above bin b (always < K_PRE)
}

// ---------------- pass 2: refine next byte within threshold bin ------------
__global__ void k_hist2(const float* __restrict__ cls, const unsigned* __restrict__ selB1,
                        unsigned* __restrict__ hist2) {
    int n = blockIdx.y;
    unsigned b1 = selB1[n];
    const float* p = cls + (size_t)n * PER;
    __shared__ unsigned lh[256];
    lh[threadIdx.x] = 0;
    __syncthreads();
    int stride = gridDim.x * blockDim.x;
    for (int i = blockIdx.x * blockDim.x + threadIdx.x; i < PER; i += stride) {
        unsigned key = keyOf(p[i]);
        if ((key >> 24) == b1) atomicAdd(&lh[(key >> 16) & 255u], 1u);
    }
    __syncthreads();
    if (lh[threadIdx.x]) atomicAdd(&hist2[n * 256 + threadIdx.x], lh[threadIdx.x]);
}

__global__ void k_sel2(const unsigned* __restrict__ hist2, const unsigned* __restrict__ selB1,
                       const unsigned* __restrict__ selAbove, unsigned* __restrict__ selT16) {
    int n = threadIdx.x;
    if (n >= NB) return;
    unsigned cum = selAbove[n]; int b = 0;
    for (b = 255; b >= 0; --b) {
        unsigned c = hist2[n * 256 + b];
        if (cum + c >= K_PRE) break;
        cum += c;
    }
    if (b < 0) b = 0;
    selT16[n] = (selB1[n] << 8) | (unsigned)b;   // 16-bit key threshold
}

// ---------------- pass 3: compact candidates (key16 >= T16) ----------------
__global__ void k_compact(const float* __restrict__ cls, const unsigned* __restrict__ selT16,
                          u64* __restrict__ cand, unsigned* __restrict__ candCount) {
    int n = blockIdx.y;
    unsigned t16 = selT16[n];
    const float* p = cls + (size_t)n * PER;
    int stride = gridDim.x * blockDim.x;
    for (int i = blockIdx.x * blockDim.x + threadIdx.x; i < PER; i += stride) {
        unsigned key = keyOf(p[i]);
        if ((key >> 16) >= t16) {
            unsigned pos = atomicAdd(&candCount[n], 1u);
            if (pos < CAP) {
                // anchor flat index in reference (h,w,a) order
                int a = i / HWSZ;          // channel
                int r = i - a * HWSZ;      // h*W+w
                unsigned idx = (unsigned)(r * AN + a);
                cand[(size_t)n * CAP + pos] = ((u64)key << 32) | (u64)(~idx);
            }
        }
    }
}

// ---------------- per-image: sort candidates, decode top-2000, partition ---
__global__ __launch_bounds__(1024)
void k_sortdecode(const float* __restrict__ reg, const float* __restrict__ anchors,
                  const int* __restrict__ pih, const int* __restrict__ piw,
                  const u64* __restrict__ cand, const unsigned* __restrict__ candCount,
                  float* __restrict__ boxes_s, float* __restrict__ scores_s) {
    int n = blockIdx.x;
    int tid = threadIdx.x;
    __shared__ u64 sb[CAP];                 // 32 KB; scan buffers alias later
    int c = (int)candCount[n]; if (c > CAP) c = CAP;
    for (int t = tid; t < CAP; t += 1024)
        sb[t] = (t < c) ? cand[(size_t)n * CAP + t] : 0ull;
    __syncthreads();

    // bitonic sort descending (primary key desc, secondary ~idx desc = idx asc)
    for (int k = 2; k <= CAP; k <<= 1) {
        for (int j = k >> 1; j > 0; j >>= 1) {
            for (int t = tid; t < CAP / 2; t += 1024) {
                int i = ((t & ~(j - 1)) << 1) | (t & (j - 1));
                int p = i | j;
                bool desc = ((i & k) == 0);
                u64 a = sb[i], b = sb[p];
                bool sw = desc ? (a < b) : (a > b);
                if (sw) { sb[i] = b; sb[p] = a; }
            }
            __syncthreads();
        }
    }

    float fh = (float)(*pih);
    float fw = (float)(*piw);

    // decode entries t0 = tid, t1 = tid+1024 into registers
    float bx[2][4]; float sc[2]; int pred[2]; int tt[2];
    tt[0] = tid; tt[1] = tid + 1024;
#pragma unroll
    for (int q = 0; q < 2; ++q) {
        int t = tt[q];
        pred[q] = 0; sc[q] = -1.0f;
        bx[q][0] = bx[q][1] = bx[q][2] = bx[q][3] = 0.f;
        if (t < K_PRE) {
            u64 e = sb[t];
            unsigned key = (unsigned)(e >> 32);
            unsigned idx = ~((unsigned)e);
            float v = valOf(key);
            float s = 1.0f / (1.0f + expf(-v));
            int a = (int)(idx % AN);
            int r = (int)(idx / AN);
            size_t base = ((size_t)(n * AN + a) * 4) * HWSZ + r;
            float dx = reg[base];
            float dy = reg[base + HWSZ];
            float dw = reg[base + 2 * (size_t)HWSZ];
            float dh = reg[base + 3 * (size_t)HWSZ];
            float4 an4 = ((const float4*)anchors)[idx];
            float wa = an4.z - an4.x, ha = an4.w - an4.y;
            float cxa = an4.x + 0.5f * wa, cya = an4.y + 0.5f * ha;
            dw = fminf(dw, BBOX_CLIP_F); dh = fminf(dh, BBOX_CLIP_F);
            float cx = dx * wa + cxa, cy = dy * ha + cya;
            float w = wa * expf(dw), h = ha * expf(dh);
            float x1 = cx - 0.5f * w, y1 = cy - 0.5f * h;
            float x2 = cx + 0.5f * w, y2 = cy + 0.5f * h;
            x1 = fminf(fmaxf(x1, 0.f), fw);
            y1 = fminf(fmaxf(y1, 0.f), fh);
            x2 = fminf(fmaxf(x2, 0.f), fw);
            y2 = fminf(fmaxf(y2, 0.f), fh);
            bool valid = ((x2 - x1) >= 1.0f) && ((y2 - y1) >= 1.0f);
            bx[q][0] = x1; bx[q][1] = y1; bx[q][2] = x2; bx[q][3] = y2;
            sc[q] = s; pred[q] = valid ? 1 : 0;
        }
    }
    __syncthreads();

    // stable partition valid-first via Hillis-Steele inclusive scan over 2048
    int* scanA = (int*)sb;          // 2048 ints = 8 KB
    int* scanB = scanA + 2048;      // next 8 KB (still inside sb's 32 KB)
    scanA[tt[0]] = pred[0];
    scanA[tt[1]] = pred[1];
    __syncthreads();
    int* cur = scanA; int* nxt = scanB;
    for (int off = 1; off < 2048; off <<= 1) {
        int a0 = cur[tt[0]] + ((tt[0] >= off) ? cur[tt[0] - off] : 0);
        int a1 = cur[tt[1]] + ((tt[1] >= off) ? cur[tt[1] - off] : 0);
        __syncthreads();
        nxt[tt[0]] = a0; nxt[tt[1]] = a1;
        __syncthreads();
        int* tmp = cur; cur = nxt; nxt = tmp;
    }
    int V = cur[2047];   // total valid among top-2000

#pragma unroll
    for (int q = 0; q < 2; ++q) {
        int t = tt[q];
        if (t < K_PRE) {
            int incl = cur[t];
            int pos = pred[q] ? (incl - 1) : (V + (t - incl));
            float4 b4; b4.x = bx[q][0]; b4.y = bx[q][1]; b4.z = bx[q][2]; b4.w = bx[q][3];
            ((float4*)boxes_s)[(size_t)n * K_PRE + pos] = b4;
            scores_s[(size_t)n * K_PRE + pos] = pred[q] ? sc[q] : -1.0f;
        }
    }
}

// ---------------- IoU suppression mask: rows x cols in 64-bit words --------
__global__ void k_mask(const float* __restrict__ boxes_s, u64* __restrict__ mask) {
    int n = blockIdx.z, cb = blockIdx.x, rb = blockIdx.y;
    int tid = threadIdx.x;
    __shared__ float4 cbox[64];
    int j = cb * 64 + tid;
    float4 z; z.x = z.y = z.z = z.w = 0.f;
    cbox[tid] = (j < K_PRE) ? ((const float4*)boxes_s)[(size_t)n * K_PRE + j] : z;
    __syncthreads();
    int r = rb * 64 + tid;
    if (r >= K_PRE) return;
    float4 rbx = ((const float4*)boxes_s)[(size_t)n * K_PRE + r];
    float areaR = (rbx.z - rbx.x) * (rbx.w - rbx.y);
    u64 bits = 0;
#pragma unroll 8
    for (int b = 0; b < 64; ++b) {
        int j2 = cb * 64 + b;
        if (j2 <= r || j2 >= K_PRE) continue;
        float4 c4 = cbox[b];
        float ix = fminf(rbx.z, c4.z) - fmaxf(rbx.x, c4.x); ix = fmaxf(ix, 0.f);
        float iy = fminf(rbx.w, c4.w) - fmaxf(rbx.y, c4.y); iy = fmaxf(iy, 0.f);
        float inter = ix * iy;
        float areaC = (c4.z - c4.x) * (c4.w - c4.y);
        float iou = inter / (areaR + areaC - inter);
        if (iou > NMS_TH) bits |= (1ull << b);
    }
    mask[((size_t)n * K_PRE + r) * 32 + cb] = bits;
}

// ---------------- sequential greedy NMS scan + output compaction -----------
__global__ void k_scan(const u64* __restrict__ mask, const float* __restrict__ boxes_s,
                       const float* __restrict__ scores_s, float* __restrict__ out) {
    int n = blockIdx.x;
    int lane = threadIdx.x;       // 64 threads, single wave
    __shared__ float ls[K_PRE];
    for (int i = lane; i < K_PRE; i += 64) ls[i] = scores_s[(size_t)n * K_PRE + i];
    __syncthreads();

    const u64* mrow = mask + (size_t)n * K_PRE * 32;
    u64 rem = 0, kept = 0;
    for (int i = 0; i < K_PRE; ++i) {
        unsigned rlo = (unsigned)(rem & 0xffffffffull);
        unsigned rhi = (unsigned)(rem >> 32);
        int src = i >> 6;
        unsigned wlo = __shfl(rlo, src, 64);
        unsigned whi = __shfl(rhi, src, 64);
        unsigned bitpos = (unsigned)(i & 63);
        unsigned word = (bitpos < 32) ? wlo : whi;
        bool removed = (word >> (bitpos & 31)) & 1u;
        if (!removed && ls[i] >= 0.f) {
            if (lane < 32) rem |= mrow[(size_t)i * 32 + lane];
            if (lane == src) kept |= (1ull << bitpos);
        }
    }

    __shared__ u64 keptw[32];
    __shared__ int pfx[32];
    if (lane < 32) keptw[lane] = kept;
    __syncthreads();
    if (lane == 0) {
        int s = 0;
        for (int w = 0; w < 32; ++w) { pfx[w] = s; s += __popcll(keptw[w]); }
    }
    __syncthreads();
    if (lane < 32) {
        u64 wb = keptw[lane];
        int rank = pfx[lane];
        while (wb) {
            int b = __ffsll((long long)wb) - 1;
            wb &= wb - 1;
            if (rank < K_POST) {
                int i = lane * 64 + b;
                float4 b4 = ((const float4*)boxes_s)[(size_t)n * K_PRE + i];
                ((float4*)out)[(size_t)n * K_POST + rank] = b4;
                out[(size_t)NB * K_POST * 4 + (size_t)n * K_POST + rank] = ls[i];
            }
            ++rank;
        }
    }
}

extern "C" void kernel_launch(void* const* d_in, const int* in_sizes, int n_in,
                              void* d_out, int out_size, void* d_ws, size_t ws_size,
                              hipStream_t stream) {
    const float* cls     = (const float*)d_in[0];
    const float* reg     = (const float*)d_in[1];
    const float* anchors = (const float*)d_in[2];
    const int*   pih     = (const int*)d_in[3];
    const int*   piw     = (const int*)d_in[4];
    float* out = (float*)d_out;

    char* w = (char*)d_ws;
    unsigned* hist1     = (unsigned*)(w + 0);          // 8*256*4 = 8192
    unsigned* hist2     = (unsigned*)(w + 8192);       // 8192
    unsigned* selB1     = (unsigned*)(w + 16384);      // 32
    unsigned* selAbove  = (unsigned*)(w + 16416);      // 32
    unsigned* selT16    = (unsigned*)(w + 16448);      // 32
    unsigned* candCount = (unsigned*)(w + 16480);      // 32
    u64*      cand      = (u64*)(w + 16512);           // 8*4096*8 = 262144
    float*    boxes_s   = (float*)(w + 278656);        // 8*2000*4*4 = 256000
    float*    scores_s  = (float*)(w + 534656);        // 8*2000*4  = 64000
    u64*      mask      = (u64*)(w + 598656);          // 8*2000*32*8 = 4096000
    // total 4,694,656 bytes

    hipMemsetAsync(w, 0, 16512, stream);                       // counters
    hipMemsetAsync(d_out, 0, (size_t)out_size * sizeof(float), stream);

    dim3 hb(256), hg(240, NB);
    k_hist1<<<hg, hb, 0, stream>>>(cls, hist1);
    k_sel1<<<1, 64, 0, stream>>>(hist1, selB1, selAbove);
    k_hist2<<<hg, hb, 0, stream>>>(cls, selB1, hist2);
    k_sel2<<<1, 64, 0, stream>>>(hist2, selB1, selAbove, selT16);
    k_compact<<<hg, hb, 0, stream>>>(cls, selT16, cand, candCount);
    k_sortdecode<<<NB, 1024, 0, stream>>>(reg, anchors, pih, piw,
                                          cand, candCount, boxes_s, scores_s);
    k_mask<<<dim3(32, 32, NB), 64, 0, stream>>>(boxes_s, mask);
    k_scan<<<NB, 64, 0, stream>>>(mask, boxes_s, scores_s, out);
    (void)in_sizes; (void)n_in; (void)ws_size;
}

// Round 2
// 509.422 us; speedup vs baseline: 1.8681x; 1.8681x over previous
//
#include <hip/hip_runtime.h>
#include <hip/hip_bf16.h>
#include <stdint.h>

typedef unsigned long long u64;

#define AN 15
#define HH 200
#define WW 320
#define HWSZ (HH*WW)          // 64000
#define PER (AN*HWSZ)         // 960000 anchors per image
#define NB 8
#define K_PRE 2000
#define K_POST 1000
#define CAP 4096
#define NMS_TH 0.7f
#define BBOX_CLIP_F 4.135166556742356f   // log(1000/16)

__device__ __forceinline__ unsigned keyOf(float f) {
    unsigned u = __float_as_uint(f);
    return (u & 0x80000000u) ? ~u : (u | 0x80000000u);
}
__device__ __forceinline__ float valOf(unsigned k) {
    unsigned u = (k & 0x80000000u) ? (k ^ 0x80000000u) : ~k;
    return __uint_as_float(u);
}

// ---------------- pass 1: 256-bin histogram of key top byte, per image -----
__global__ void k_hist1(const float4* __restrict__ cls4, unsigned* __restrict__ hist) {
    int n = blockIdx.y;
    const float4* p = cls4 + (size_t)n * (PER / 4);
    __shared__ unsigned lh[256];
    lh[threadIdx.x] = 0;
    __syncthreads();
    int stride = gridDim.x * blockDim.x;
    for (int i = blockIdx.x * blockDim.x + threadIdx.x; i < PER / 4; i += stride) {
        float4 v = p[i];
        atomicAdd(&lh[keyOf(v.x) >> 24], 1u);
        atomicAdd(&lh[keyOf(v.y) >> 24], 1u);
        atomicAdd(&lh[keyOf(v.z) >> 24], 1u);
        atomicAdd(&lh[keyOf(v.w) >> 24], 1u);
    }
    __syncthreads();
    if (lh[threadIdx.x]) atomicAdd(&hist[n * 256 + threadIdx.x], lh[threadIdx.x]);
}

// parallel suffix-scan selection of the top-byte threshold bin
__global__ void k_sel1(const unsigned* __restrict__ hist,
                       unsigned* __restrict__ selB1, unsigned* __restrict__ selAbove) {
    int n = blockIdx.x, t = threadIdx.x;
    __shared__ unsigned sfx[256];
    sfx[t] = hist[n * 256 + t];
    __syncthreads();
    for (int off = 1; off < 256; off <<= 1) {
        unsigned v = sfx[t] + ((t + off < 256) ? sfx[t + off] : 0u);
        __syncthreads(); sfx[t] = v; __syncthreads();
    }
    unsigned above = (t < 255) ? sfx[t + 1] : 0u;
    if (sfx[t] >= K_PRE && above < K_PRE) { selB1[n] = (unsigned)t; selAbove[n] = above; }
}

// ---------------- pass 2: refine next byte within threshold bin ------------
__global__ void k_hist2(const float4* __restrict__ cls4, const unsigned* __restrict__ selB1,
                        unsigned* __restrict__ hist2) {
    int n = blockIdx.y;
    unsigned b1 = selB1[n];
    const float4* p = cls4 + (size_t)n * (PER / 4);
    __shared__ unsigned lh[256];
    lh[threadIdx.x] = 0;
    __syncthreads();
    int stride = gridDim.x * blockDim.x;
    for (int i = blockIdx.x * blockDim.x + threadIdx.x; i < PER / 4; i += stride) {
        float4 v = p[i];
        unsigned k0 = keyOf(v.x), k1 = keyOf(v.y), k2 = keyOf(v.z), k3 = keyOf(v.w);
        if ((k0 >> 24) == b1) atomicAdd(&lh[(k0 >> 16) & 255u], 1u);
        if ((k1 >> 24) == b1) atomicAdd(&lh[(k1 >> 16) & 255u], 1u);
        if ((k2 >> 24) == b1) atomicAdd(&lh[(k2 >> 16) & 255u], 1u);
        if ((k3 >> 24) == b1) atomicAdd(&lh[(k3 >> 16) & 255u], 1u);
    }
    __syncthreads();
    if (lh[threadIdx.x]) atomicAdd(&hist2[n * 256 + threadIdx.x], lh[threadIdx.x]);
}

__global__ void k_sel2(const unsigned* __restrict__ hist2, const unsigned* __restrict__ selB1,
                       const unsigned* __restrict__ selAbove, unsigned* __restrict__ selT16) {
    int n = blockIdx.x, t = threadIdx.x;
    __shared__ unsigned sfx[256];
    sfx[t] = hist2[n * 256 + t];
    __syncthreads();
    for (int off = 1; off < 256; off <<= 1) {
        unsigned v = sfx[t] + ((t + off < 256) ? sfx[t + off] : 0u);
        __syncthreads(); sfx[t] = v; __syncthreads();
    }
    unsigned base = selAbove[n];
    unsigned above = (t < 255) ? sfx[t + 1] : 0u;
    if (base + sfx[t] >= K_PRE && base + above < K_PRE)
        selT16[n] = (selB1[n] << 8) | (unsigned)t;
}

// ---------------- pass 3: compact candidates (key16 >= T16) ----------------
__global__ void k_compact(const float4* __restrict__ cls4, const unsigned* __restrict__ selT16,
                          u64* __restrict__ cand, unsigned* __restrict__ candCount) {
    int n = blockIdx.y;
    unsigned t16 = selT16[n];
    const float4* p = cls4 + (size_t)n * (PER / 4);
    int stride = gridDim.x * blockDim.x;
    for (int i4 = blockIdx.x * blockDim.x + threadIdx.x; i4 < PER / 4; i4 += stride) {
        float4 v = p[i4];
        float e[4] = {v.x, v.y, v.z, v.w};
        int i0 = i4 * 4;
        int a = i0 / HWSZ;                 // uniform across the 4 (HWSZ % 4 == 0)
        int r0 = i0 - a * HWSZ;
#pragma unroll
        for (int c = 0; c < 4; ++c) {
            unsigned key = keyOf(e[c]);
            if ((key >> 16) >= t16) {
                unsigned pos = atomicAdd(&candCount[n], 1u);
                if (pos < CAP) {
                    unsigned idx = (unsigned)((r0 + c) * AN + a);
                    cand[(size_t)n * CAP + pos] = ((u64)key << 32) | (u64)(~idx);
                }
            }
        }
    }
}

// ---------------- per-image: sort candidates, decode top-2000, partition ---
__global__ __launch_bounds__(1024)
void k_sortdecode(const float* __restrict__ reg, const float* __restrict__ anchors,
                  const int* __restrict__ pih, const int* __restrict__ piw,
                  const u64* __restrict__ cand, const unsigned* __restrict__ candCount,
                  float* __restrict__ boxes_s, float* __restrict__ scores_s) {
    int n = blockIdx.x;
    int tid = threadIdx.x;
    __shared__ u64 sb[CAP];                 // 32 KB; scan buffers alias later
    int c = (int)candCount[n]; if (c > CAP) c = CAP;
    for (int t = tid; t < CAP; t += 1024)
        sb[t] = (t < c) ? cand[(size_t)n * CAP + t] : 0ull;
    __syncthreads();

    // bitonic sort descending (primary key desc, secondary ~idx desc = idx asc)
    for (int k = 2; k <= CAP; k <<= 1) {
        for (int j = k >> 1; j > 0; j >>= 1) {
            for (int t = tid; t < CAP / 2; t += 1024) {
                int i = ((t & ~(j - 1)) << 1) | (t & (j - 1));
                int p = i | j;
                bool desc = ((i & k) == 0);
                u64 a = sb[i], b = sb[p];
                bool sw = desc ? (a < b) : (a > b);
                if (sw) { sb[i] = b; sb[p] = a; }
            }
            __syncthreads();
        }
    }

    float fh = (float)(*pih);
    float fw = (float)(*piw);

    // decode entries t0 = tid, t1 = tid+1024 into registers
    float bx[2][4]; float sc[2]; int pred[2]; int tt[2];
    tt[0] = tid; tt[1] = tid + 1024;
#pragma unroll
    for (int q = 0; q < 2; ++q) {
        int t = tt[q];
        pred[q] = 0; sc[q] = -1.0f;
        bx[q][0] = bx[q][1] = bx[q][2] = bx[q][3] = 0.f;
        if (t < K_PRE) {
            u64 e = sb[t];
            unsigned key = (unsigned)(e >> 32);
            unsigned idx = ~((unsigned)e);
            float v = valOf(key);
            float s = 1.0f / (1.0f + expf(-v));
            int a = (int)(idx % AN);
            int r = (int)(idx / AN);
            size_t base = ((size_t)(n * AN + a) * 4) * HWSZ + r;
            float dx = reg[base];
            float dy = reg[base + HWSZ];
            float dw = reg[base + 2 * (size_t)HWSZ];
            float dh = reg[base + 3 * (size_t)HWSZ];
            float4 an4 = ((const float4*)anchors)[idx];
            float wa = an4.z - an4.x, ha = an4.w - an4.y;
            float cxa = an4.x + 0.5f * wa, cya = an4.y + 0.5f * ha;
            dw = fminf(dw, BBOX_CLIP_F); dh = fminf(dh, BBOX_CLIP_F);
            float cx = dx * wa + cxa, cy = dy * ha + cya;
            float w = wa * expf(dw), h = ha * expf(dh);
            float x1 = cx - 0.5f * w, y1 = cy - 0.5f * h;
            float x2 = cx + 0.5f * w, y2 = cy + 0.5f * h;
            x1 = fminf(fmaxf(x1, 0.f), fw);
            y1 = fminf(fmaxf(y1, 0.f), fh);
            x2 = fminf(fmaxf(x2, 0.f), fw);
            y2 = fminf(fmaxf(y2, 0.f), fh);
            bool valid = ((x2 - x1) >= 1.0f) && ((y2 - y1) >= 1.0f);
            bx[q][0] = x1; bx[q][1] = y1; bx[q][2] = x2; bx[q][3] = y2;
            sc[q] = s; pred[q] = valid ? 1 : 0;
        }
    }
    __syncthreads();

    // stable partition valid-first via Hillis-Steele inclusive scan over 2048
    int* scanA = (int*)sb;          // 2048 ints = 8 KB
    int* scanB = scanA + 2048;      // next 8 KB (still inside sb's 32 KB)
    scanA[tt[0]] = pred[0];
    scanA[tt[1]] = pred[1];
    __syncthreads();
    int* cur = scanA; int* nxt = scanB;
    for (int off = 1; off < 2048; off <<= 1) {
        int a0 = cur[tt[0]] + ((tt[0] >= off) ? cur[tt[0] - off] : 0);
        int a1 = cur[tt[1]] + ((tt[1] >= off) ? cur[tt[1] - off] : 0);
        __syncthreads();
        nxt[tt[0]] = a0; nxt[tt[1]] = a1;
        __syncthreads();
        int* tmp = cur; cur = nxt; nxt = tmp;
    }
    int V = cur[2047];   // total valid among top-2000

#pragma unroll
    for (int q = 0; q < 2; ++q) {
        int t = tt[q];
        if (t < K_PRE) {
            int incl = cur[t];
            int pos = pred[q] ? (incl - 1) : (V + (t - incl));
            float4 b4; b4.x = bx[q][0]; b4.y = bx[q][1]; b4.z = bx[q][2]; b4.w = bx[q][3];
            ((float4*)boxes_s)[(size_t)n * K_PRE + pos] = b4;
            scores_s[(size_t)n * K_PRE + pos] = pred[q] ? sc[q] : -1.0f;
        }
    }
}

// ---------------- IoU suppression mask: rows x cols in 64-bit words --------
__global__ void k_mask(const float* __restrict__ boxes_s, u64* __restrict__ mask) {
    int n = blockIdx.z, cb = blockIdx.x, rb = blockIdx.y;
    int tid = threadIdx.x;
    __shared__ float4 cbox[64];
    int j = cb * 64 + tid;
    float4 z; z.x = z.y = z.z = z.w = 0.f;
    cbox[tid] = (j < K_PRE) ? ((const float4*)boxes_s)[(size_t)n * K_PRE + j] : z;
    __syncthreads();
    int r = rb * 64 + tid;
    if (r >= K_PRE) return;
    float4 rbx = ((const float4*)boxes_s)[(size_t)n * K_PRE + r];
    float areaR = (rbx.z - rbx.x) * (rbx.w - rbx.y);
    u64 bits = 0;
#pragma unroll 8
    for (int b = 0; b < 64; ++b) {
        int j2 = cb * 64 + b;
        if (j2 <= r || j2 >= K_PRE) continue;
        float4 c4 = cbox[b];
        float ix = fminf(rbx.z, c4.z) - fmaxf(rbx.x, c4.x); ix = fmaxf(ix, 0.f);
        float iy = fminf(rbx.w, c4.w) - fmaxf(rbx.y, c4.y); iy = fmaxf(iy, 0.f);
        float inter = ix * iy;
        float areaC = (c4.z - c4.x) * (c4.w - c4.y);
        float iou = inter / (areaR + areaC - inter);
        if (iou > NMS_TH) bits |= (1ull << b);
    }
    mask[((size_t)n * K_PRE + r) * 32 + cb] = bits;
}

// ---------------- greedy NMS scan, block-batched (latency-optimized) -------
// 1 wave per image. 32 blocks of 64 boxes. Per block:
//   (a) one coalesced load of the 64 diagonal mask words,
//   (b) 64-step in-register serial decision loop (readlane broadcasts only),
//   (c) batched, branch-free, independent loads to push suppression forward.
__global__ void k_scan(const u64* __restrict__ mask, const float* __restrict__ boxes_s,
                       const float* __restrict__ scores_s, float* __restrict__ out) {
    int n = blockIdx.x;
    int lane = threadIdx.x;       // 64 threads, single wave
    int j = lane & 31;            // removed-bitmap word owned by this lane (dup in both halves)
    const u64* mrow = mask + (size_t)n * K_PRE * 32;

    __shared__ float ls[2048];
    for (int i = lane; i < 2048; i += 64)
        ls[i] = (i < K_PRE) ? scores_s[(size_t)n * K_PRE + i] : -1.0f;
    __syncthreads();

    u64 rem = 0;                  // word j of the removed bitmap
    int kept_total = 0;

    for (int blk = 0; blk < 32; ++blk) {
        int rowbase = blk * 64;
        // broadcast removed-word for this block from lane 'blk'
        unsigned rl = __shfl((unsigned)rem, blk, 64);
        unsigned rh = __shfl((unsigned)(rem >> 32), blk, 64);
        u64 removed = ((u64)rh << 32) | (u64)rl;

        // diagonal mask word: row rowbase+lane, col-block blk
        u64 diag = (rowbase + lane < K_PRE) ? mrow[(size_t)(rowbase + lane) * 32 + blk] : 0ull;
        u64 valid64 = __ballot(ls[rowbase + lane] >= 0.0f);

        // serial greedy over the 64 boxes of this block, all in registers.
        // state is identical on every lane (broadcast values), so no divergence.
        u64 kept64 = 0;
#pragma unroll
        for (int b = 0; b < 64; ++b) {
            unsigned dl = __shfl((unsigned)diag, b, 64);
            unsigned dh = __shfl((unsigned)(diag >> 32), b, 64);
            u64 d = ((u64)dh << 32) | (u64)dl;
            u64 on = (~(removed >> b) & (valid64 >> b)) & 1ull;
            kept64 |= on << b;
            removed |= d & (0ull - on);
        }

        // emit kept boxes of this block (rank < K_POST only)
        if ((kept64 >> lane) & 1ull) {
            int rank = kept_total + (int)__popcll(kept64 & ((1ull << lane) - 1ull));
            if (rank < K_POST) {
                float4 b4 = ((const float4*)boxes_s)[(size_t)n * K_PRE + rowbase + lane];
                ((float4*)out)[(size_t)n * K_POST + rank] = b4;
                out[(size_t)NB * K_POST * 4 + (size_t)n * K_POST + rank] = ls[rowbase + lane];
            }
        }
        kept_total += (int)__popcll(kept64);
        if (kept_total >= K_POST || blk == 31) break;

        // push suppression to future blocks: rem_j |= OR over kept b of mask[row_b][j]
        // unconditional independent loads + masked OR -> full memory-level parallelism.
        int bo = (lane >> 5) * 32;    // halves of the wave split the 64 rows
        u64 acc = 0;
#pragma unroll 8
        for (int b = 0; b < 32; ++b) {
            int bb = bo + b;
            u64 m = mrow[(size_t)(rowbase + bb) * 32 + j];   // rows <= 1983 here, in-bounds
            acc |= m & (0ull - ((kept64 >> bb) & 1ull));
        }
        unsigned al = __shfl_xor((unsigned)acc, 32, 64);
        unsigned ah = __shfl_xor((unsigned)(acc >> 32), 32, 64);
        rem |= acc | (((u64)ah << 32) | (u64)al);
    }
}

extern "C" void kernel_launch(void* const* d_in, const int* in_sizes, int n_in,
                              void* d_out, int out_size, void* d_ws, size_t ws_size,
                              hipStream_t stream) {
    const float* cls     = (const float*)d_in[0];
    const float* reg     = (const float*)d_in[1];
    const float* anchors = (const float*)d_in[2];
    const int*   pih     = (const int*)d_in[3];
    const int*   piw     = (const int*)d_in[4];
    float* out = (float*)d_out;

    char* w = (char*)d_ws;
    unsigned* hist1     = (unsigned*)(w + 0);          // 8*256*4 = 8192
    unsigned* hist2     = (unsigned*)(w + 8192);       // 8192
    unsigned* selB1     = (unsigned*)(w + 16384);      // 32
    unsigned* selAbove  = (unsigned*)(w + 16416);      // 32
    unsigned* selT16    = (unsigned*)(w + 16448);      // 32
    unsigned* candCount = (unsigned*)(w + 16480);      // 32
    u64*      cand      = (u64*)(w + 16512);           // 8*4096*8 = 262144
    float*    boxes_s   = (float*)(w + 278656);        // 8*2000*4*4 = 256000
    float*    scores_s  = (float*)(w + 534656);        // 8*2000*4  = 64000
    u64*      mask      = (u64*)(w + 598656);          // 8*2000*32*8 = 4096000
    // total 4,694,656 bytes

    hipMemsetAsync(w, 0, 16512, stream);                       // counters
    hipMemsetAsync(d_out, 0, (size_t)out_size * sizeof(float), stream);

    dim3 hb(256), hg(256, NB);
    k_hist1<<<hg, hb, 0, stream>>>((const float4*)cls, hist1);
    k_sel1<<<NB, 256, 0, stream>>>(hist1, selB1, selAbove);
    k_hist2<<<hg, hb, 0, stream>>>((const float4*)cls, selB1, hist2);
    k_sel2<<<NB, 256, 0, stream>>>(hist2, selB1, selAbove, selT16);
    k_compact<<<hg, hb, 0, stream>>>((const float4*)cls, selT16, cand, candCount);
    k_sortdecode<<<NB, 1024, 0, stream>>>(reg, anchors, pih, piw,
                                          cand, candCount, boxes_s, scores_s);
    k_mask<<<dim3(32, 32, NB), 64, 0, stream>>>(boxes_s, mask);
    k_scan<<<NB, 64, 0, stream>>>(mask, boxes_s, scores_s, out);
    (void)in_sizes; (void)n_in; (void)ws_size;
}

// Round 3
// 446.479 us; speedup vs baseline: 2.1315x; 1.1410x over previous
//
#include <hip/hip_runtime.h>
#include <hip/hip_bf16.h>
#include <stdint.h>

typedef unsigned long long u64;

#define AN 15
#define HH 200
#define WW 320
#define HWSZ (HH*WW)          // 64000
#define PER (AN*HWSZ)         // 960000 anchors per image
#define NB 8
#define K_PRE 2000
#define K_POST 1000
#define CAP 6144
#define SORTN 8192
#define HBINS 4096
#define HBLK 24               // hist partial blocks per image
#define NMS_TH 0.7f
#define BBOX_CLIP_F 4.135166556742356f   // log(1000/16)

__device__ __forceinline__ unsigned keyOf(float f) {
    unsigned u = __float_as_uint(f);
    return (u & 0x80000000u) ? ~u : (u | 0x80000000u);
}
__device__ __forceinline__ float valOf(unsigned k) {
    unsigned u = (k & 0x80000000u) ? (k ^ 0x80000000u) : ~k;
    return __uint_as_float(u);
}

// ---------- pass 1: per-block private 12-bit histogram (no global atomics) --
__global__ __launch_bounds__(256)
void k_hist(const float4* __restrict__ cls4, unsigned* __restrict__ bh) {
    int n = blockIdx.y;
    __shared__ unsigned lh[HBINS];
    for (int b = threadIdx.x; b < HBINS; b += 256) lh[b] = 0;
    __syncthreads();
    const float4* p = cls4 + (size_t)n * (PER / 4);
    int stride = gridDim.x * 256;
    for (int i = blockIdx.x * 256 + threadIdx.x; i < PER / 4; i += stride) {
        float4 v = p[i];
        atomicAdd(&lh[keyOf(v.x) >> 20], 1u);
        atomicAdd(&lh[keyOf(v.y) >> 20], 1u);
        atomicAdd(&lh[keyOf(v.z) >> 20], 1u);
        atomicAdd(&lh[keyOf(v.w) >> 20], 1u);
    }
    __syncthreads();
    unsigned* dst = bh + ((size_t)n * HBLK + blockIdx.x) * HBINS;
    for (int b = threadIdx.x; b < HBINS; b += 256) dst[b] = lh[b];
}

// ---------- fused reduce + suffix-scan -> 12-bit threshold ------------------
__global__ __launch_bounds__(1024)
void k_sel(const unsigned* __restrict__ bh, unsigned* __restrict__ selT12) {
    int n = blockIdx.x, t = threadIdx.x;
    __shared__ unsigned L[1024];
    unsigned c0 = 0, c1 = 0, c2 = 0, c3 = 0;
    const unsigned* base = bh + (size_t)n * HBLK * HBINS + 4 * t;
    for (int blk = 0; blk < HBLK; ++blk) {
        uint4 v = *(const uint4*)(base + (size_t)blk * HBINS);
        c0 += v.x; c1 += v.y; c2 += v.z; c3 += v.w;
    }
    unsigned s3 = c3, s2 = c2 + s3, s1 = c1 + s2, s0 = c0 + s1;
    L[t] = s0;
    __syncthreads();
    for (int off = 1; off < 1024; off <<= 1) {
        unsigned v = L[t] + ((t + off < 1024) ? L[t + off] : 0u);
        __syncthreads(); L[t] = v; __syncthreads();
    }
    unsigned tail = (t < 1023) ? L[t + 1] : 0u;
    unsigned sf0 = s0 + tail, sf1 = s1 + tail, sf2 = s2 + tail, sf3 = s3 + tail;
    if (sf0 >= K_PRE && sf1 < K_PRE) selT12[n] = 4u * t + 0u;
    if (sf1 >= K_PRE && sf2 < K_PRE) selT12[n] = 4u * t + 1u;
    if (sf2 >= K_PRE && sf3 < K_PRE) selT12[n] = 4u * t + 2u;
    if (sf3 >= K_PRE && tail < K_PRE) selT12[n] = 4u * t + 3u;
}

// ---------- compact candidates (key12 >= T12) -------------------------------
__global__ __launch_bounds__(256)
void k_compact(const float4* __restrict__ cls4, const unsigned* __restrict__ selT12,
               u64* __restrict__ cand, unsigned* __restrict__ candCount) {
    int n = blockIdx.y;
    unsigned t12 = selT12[n];
    const float4* p = cls4 + (size_t)n * (PER / 4);
    int stride = gridDim.x * 256;
    for (int i4 = blockIdx.x * 256 + threadIdx.x; i4 < PER / 4; i4 += stride) {
        float4 v = p[i4];
        float e[4] = {v.x, v.y, v.z, v.w};
        int i0 = i4 * 4;
        int a = i0 / HWSZ;                 // uniform across the 4 (HWSZ % 4 == 0)
        int r0 = i0 - a * HWSZ;
#pragma unroll
        for (int c = 0; c < 4; ++c) {
            unsigned key = keyOf(e[c]);
            if ((key >> 20) >= t12) {
                unsigned pos = atomicAdd(&candCount[n], 1u);
                if (pos < CAP) {
                    unsigned idx = (unsigned)((r0 + c) * AN + a);
                    cand[(size_t)n * CAP + pos] = ((u64)key << 32) | (u64)(~idx);
                }
            }
        }
    }
}

// ---------- per-image: bitonic sort, decode top-2000, stable partition ------
__global__ __launch_bounds__(1024)
void k_sortdecode(const float* __restrict__ reg, const float* __restrict__ anchors,
                  const int* __restrict__ pih, const int* __restrict__ piw,
                  const u64* __restrict__ cand, const unsigned* __restrict__ candCount,
                  float* __restrict__ boxes_s, float* __restrict__ scores_s) {
    int n = blockIdx.x;
    int tid = threadIdx.x;
    __shared__ u64 sb[SORTN];               // 64 KB; scan buffers alias later
    int c = (int)candCount[n]; if (c > CAP) c = CAP;
    for (int t = tid; t < SORTN; t += 1024)
        sb[t] = (t < c) ? cand[(size_t)n * CAP + t] : 0ull;
    __syncthreads();

    // bitonic sort descending (primary key desc, secondary ~idx desc = idx asc)
    for (int k = 2; k <= SORTN; k <<= 1) {
        for (int j = k >> 1; j > 0; j >>= 1) {
            for (int t = tid; t < SORTN / 2; t += 1024) {
                int i = ((t & ~(j - 1)) << 1) | (t & (j - 1));
                int p = i | j;
                bool desc = ((i & k) == 0);
                u64 a = sb[i], b = sb[p];
                bool sw = desc ? (a < b) : (a > b);
                if (sw) { sb[i] = b; sb[p] = a; }
            }
            __syncthreads();
        }
    }

    float fh = (float)(*pih);
    float fw = (float)(*piw);

    float bx[2][4]; float sc[2]; int pred[2]; int tt[2];
    tt[0] = tid; tt[1] = tid + 1024;
#pragma unroll
    for (int q = 0; q < 2; ++q) {
        int t = tt[q];
        pred[q] = 0; sc[q] = -1.0f;
        bx[q][0] = bx[q][1] = bx[q][2] = bx[q][3] = 0.f;
        if (t < K_PRE) {
            u64 e = sb[t];
            unsigned key = (unsigned)(e >> 32);
            unsigned idx = ~((unsigned)e);
            float v = valOf(key);
            float s = 1.0f / (1.0f + expf(-v));
            int a = (int)(idx % AN);
            int r = (int)(idx / AN);
            size_t base = ((size_t)(n * AN + a) * 4) * HWSZ + r;
            float dx = reg[base];
            float dy = reg[base + HWSZ];
            float dw = reg[base + 2 * (size_t)HWSZ];
            float dh = reg[base + 3 * (size_t)HWSZ];
            float4 an4 = ((const float4*)anchors)[idx];
            float wa = an4.z - an4.x, ha = an4.w - an4.y;
            float cxa = an4.x + 0.5f * wa, cya = an4.y + 0.5f * ha;
            dw = fminf(dw, BBOX_CLIP_F); dh = fminf(dh, BBOX_CLIP_F);
            float cx = dx * wa + cxa, cy = dy * ha + cya;
            float w = wa * expf(dw), h = ha * expf(dh);
            float x1 = cx - 0.5f * w, y1 = cy - 0.5f * h;
            float x2 = cx + 0.5f * w, y2 = cy + 0.5f * h;
            x1 = fminf(fmaxf(x1, 0.f), fw);
            y1 = fminf(fmaxf(y1, 0.f), fh);
            x2 = fminf(fmaxf(x2, 0.f), fw);
            y2 = fminf(fmaxf(y2, 0.f), fh);
            bool valid = ((x2 - x1) >= 1.0f) && ((y2 - y1) >= 1.0f);
            bx[q][0] = x1; bx[q][1] = y1; bx[q][2] = x2; bx[q][3] = y2;
            sc[q] = s; pred[q] = valid ? 1 : 0;
        }
    }
    __syncthreads();

    // stable partition valid-first via Hillis-Steele inclusive scan over 2048
    int* scanA = (int*)sb;
    int* scanB = scanA + 2048;
    scanA[tt[0]] = pred[0];
    scanA[tt[1]] = pred[1];
    __syncthreads();
    int* cur = scanA; int* nxt = scanB;
    for (int off = 1; off < 2048; off <<= 1) {
        int a0 = cur[tt[0]] + ((tt[0] >= off) ? cur[tt[0] - off] : 0);
        int a1 = cur[tt[1]] + ((tt[1] >= off) ? cur[tt[1] - off] : 0);
        __syncthreads();
        nxt[tt[0]] = a0; nxt[tt[1]] = a1;
        __syncthreads();
        int* tmp = cur; cur = nxt; nxt = tmp;
    }
    int V = cur[2047];

#pragma unroll
    for (int q = 0; q < 2; ++q) {
        int t = tt[q];
        if (t < K_PRE) {
            int incl = cur[t];
            int pos = pred[q] ? (incl - 1) : (V + (t - incl));
            float4 b4; b4.x = bx[q][0]; b4.y = bx[q][1]; b4.z = bx[q][2]; b4.w = bx[q][3];
            ((float4*)boxes_s)[(size_t)n * K_PRE + pos] = b4;
            scores_s[(size_t)n * K_PRE + pos] = pred[q] ? sc[q] : -1.0f;
        }
    }
}

// ---------- transposed IoU mask: maskT[n][rowblk][col] = incoming edges -----
// bit b of maskT[n][rb][c] = (IoU(row rb*64+b, col c) > th) && (row < col)
__global__ __launch_bounds__(256)
void k_maskT(const float* __restrict__ boxes_s, u64* __restrict__ maskT) {
    int n = blockIdx.y, cb = blockIdx.x;
    int lane = threadIdx.x & 63, w = threadIdx.x >> 6;
    __shared__ float4 rowbuf[4][64];
    int c = cb * 64 + lane;
    bool cok = c < K_PRE;
    float4 c4;
    if (cok) c4 = ((const float4*)boxes_s)[(size_t)n * K_PRE + c];
    else { c4.x = c4.y = c4.z = c4.w = 0.f; }
    float areaC = (c4.z - c4.x) * (c4.w - c4.y);

    for (int rb = w; rb < 32; rb += 4) {
        u64 bits = 0;
        if (rb <= cb) {
            int r = rb * 64 + lane;
            float4 r4;
            if (r < K_PRE) r4 = ((const float4*)boxes_s)[(size_t)n * K_PRE + r];
            else { r4.x = r4.y = r4.z = r4.w = 0.f; }
            rowbuf[w][lane] = r4;
            if (cok) {
                int bmax = c - rb * 64; if (bmax > 64) bmax = 64;
                for (int b = 0; b < bmax; ++b) {
                    float4 q = rowbuf[w][b];
                    float ix = fminf(c4.z, q.z) - fmaxf(c4.x, q.x); ix = fmaxf(ix, 0.f);
                    float iy = fminf(c4.w, q.w) - fmaxf(c4.y, q.y); iy = fmaxf(iy, 0.f);
                    float inter = ix * iy;
                    float areaR = (q.z - q.x) * (q.w - q.y);
                    float iou = inter / (areaR + areaC - inter);
                    if (iou > NMS_TH) bits |= (1ull << b);
                }
            }
        }
        maskT[((size_t)n * 32 + rb) * 2048 + c] = bits;
    }
}

// ---------- greedy NMS: ballot-fixpoint per 64-block, zero shuffle chains ---
__global__ __launch_bounds__(64)
void k_scanT(const u64* __restrict__ maskT, const float* __restrict__ boxes_s,
             const float* __restrict__ scores_s, float* __restrict__ out) {
    int n = blockIdx.x;
    int lane = threadIdx.x;       // 64 threads, single wave
    __shared__ float ls[2048];
    __shared__ u64 keptw[32];
    for (int i = lane; i < 2048; i += 64)
        ls[i] = (i < K_PRE) ? scores_s[(size_t)n * K_PRE + i] : -1.0f;
    if (lane < 32) keptw[lane] = 0ull;
    __syncthreads();

    const u64* mb = maskT + (size_t)n * 32 * 2048;
    int kept_total = 0;

    // prefetch incoming words for block 0
    u64 wv[32];
#pragma unroll
    for (int rb = 0; rb < 32; ++rb) wv[rb] = mb[(size_t)rb * 2048 + lane];

    for (int f = 0; f < 32; ++f) {
        int c = f * 64 + lane;

        // issue next block's loads early (hide latency under fixpoint/emit)
        u64 wn[32];
        if (f < 31) {
            int cn = c + 64;
#pragma unroll
            for (int rb = 0; rb < 32; ++rb) wn[rb] = mb[(size_t)rb * 2048 + cn];
        }

        // external suppression: OR over earlier blocks of (incoming & kept)
        // keptw[rb>=f] == 0, so unconditional AND is safe.
        u64 hit = 0;
#pragma unroll
        for (int rb = 0; rb < 32; ++rb) hit |= (wv[rb] & keptw[rb]);
        bool ext = hit != 0ull;
        u64 diag = wv[f];          // in-block incoming edges (bits b < lane)

        bool v = (ls[c] >= 0.0f) && !ext;
        u64 kept = __ballot(v);
        // fixpoint of keep[i] = v[i] & !(in_i & kept) — unique solution = greedy
        while (true) {
            u64 nk = __ballot(v && ((diag & kept) == 0ull));
            if (nk == kept) break;
            kept = nk;
        }

        if ((kept >> lane) & 1ull) {
            int rank = kept_total + (int)__popcll(kept & ((1ull << lane) - 1ull));
            if (rank < K_POST) {
                float4 b4 = ((const float4*)boxes_s)[(size_t)n * K_PRE + c];
                ((float4*)out)[(size_t)n * K_POST + rank] = b4;
                out[(size_t)NB * K_POST * 4 + (size_t)n * K_POST + rank] = ls[c];
            }
        }
        kept_total += (int)__popcll(kept);
        if (lane == 0) keptw[f] = kept;
        __syncthreads();
        if (kept_total >= K_POST || f == 31) break;
#pragma unroll
        for (int rb = 0; rb < 32; ++rb) wv[rb] = wn[rb];
    }
}

extern "C" void kernel_launch(void* const* d_in, const int* in_sizes, int n_in,
                              void* d_out, int out_size, void* d_ws, size_t ws_size,
                              hipStream_t stream) {
    const float* cls     = (const float*)d_in[0];
    const float* reg     = (const float*)d_in[1];
    const float* anchors = (const float*)d_in[2];
    const int*   pih     = (const int*)d_in[3];
    const int*   piw     = (const int*)d_in[4];
    float* out = (float*)d_out;

    char* w = (char*)d_ws;
    // Region A (4 MiB), time-multiplexed:
    //   [0, 3 MiB)        blockhist   (k_hist -> k_sel)
    //   [3 MiB, +384 KiB) cand        (k_compact -> k_sortdecode)
    //   [0, 4 MiB)        maskT       (k_maskT -> k_scanT, clobbers both)
    unsigned* bh      = (unsigned*)(w + 0);            // 8*24*4096*4 = 3,145,728
    u64*      cand    = (u64*)(w + 3145728);           // 8*6144*8   =   393,216
    u64*      maskT   = (u64*)(w + 0);                 // 8*32*2048*8 = 4,194,304
    unsigned* selT12    = (unsigned*)(w + 4194304);    // 32
    unsigned* candCount = (unsigned*)(w + 4194368);    // 32
    float*    boxes_s   = (float*)(w + 4194432);       // 8*2000*4*4 = 256,000
    float*    scores_s  = (float*)(w + 4450432);       // 8*2000*4   =  64,000
    // total 4,514,432 bytes (< 4,694,656 proven available)

    hipMemsetAsync(w + 4194304, 0, 128, stream);               // selT12 + candCount
    hipMemsetAsync(d_out, 0, (size_t)out_size * sizeof(float), stream);

    k_hist<<<dim3(HBLK, NB), 256, 0, stream>>>((const float4*)cls, bh);
    k_sel<<<NB, 1024, 0, stream>>>(bh, selT12);
    k_compact<<<dim3(64, NB), 256, 0, stream>>>((const float4*)cls, selT12, cand, candCount);
    k_sortdecode<<<NB, 1024, 0, stream>>>(reg, anchors, pih, piw,
                                          cand, candCount, boxes_s, scores_s);
    k_maskT<<<dim3(32, NB), 256, 0, stream>>>(boxes_s, maskT);
    k_scanT<<<NB, 64, 0, stream>>>(maskT, boxes_s, scores_s, out);
    (void)in_sizes; (void)n_in; (void)ws_size;
}

// Round 4
// 215.585 us; speedup vs baseline: 4.4143x; 2.0710x over previous
//
#include <hip/hip_runtime.h>
#include <hip/hip_bf16.h>
#include <stdint.h>

typedef unsigned long long u64;

#define AN 15
#define HH 200
#define WW 320
#define HWSZ (HH*WW)          // 64000
#define PER (AN*HWSZ)         // 960000 anchors per image
#define NB 8
#define K_PRE 2000
#define K_POST 1000
#define SORTN 8192
#define HBINS 4096
#define HBLK 32               // hist partial blocks per image
#define CBLK 32               // compact blocks per image
#define SLICE (SORTN/CBLK)    // 256 candidate slots per compact block
#define NMS_TH 0.7f
#define BBOX_CLIP_F 4.135166556742356f   // log(1000/16)

__device__ __forceinline__ unsigned keyOfU(unsigned u) {
    return (u & 0x80000000u) ? ~u : (u | 0x80000000u);
}
__device__ __forceinline__ float valOf(unsigned k) {
    unsigned u = (k & 0x80000000u) ? (k ^ 0x80000000u) : ~k;
    return __uint_as_float(u);
}

// ---------- pass 1: per-block private 12-bit histogram (no global atomics) --
__global__ __launch_bounds__(256)
void k_hist(const uint4* __restrict__ cls4, unsigned* __restrict__ bh) {
    int n = blockIdx.y;
    __shared__ unsigned lh[HBINS];
    for (int b = threadIdx.x; b < HBINS; b += 256) lh[b] = 0;
    __syncthreads();
    const uint4* p = cls4 + (size_t)n * (PER / 4);
    int stride = gridDim.x * 256;
    int i = blockIdx.x * 256 + threadIdx.x;
    for (; i + stride < PER / 4; i += 2 * stride) {
        uint4 a = p[i];
        uint4 b = p[i + stride];
        atomicAdd(&lh[keyOfU(a.x) >> 20], 1u);
        atomicAdd(&lh[keyOfU(a.y) >> 20], 1u);
        atomicAdd(&lh[keyOfU(a.z) >> 20], 1u);
        atomicAdd(&lh[keyOfU(a.w) >> 20], 1u);
        atomicAdd(&lh[keyOfU(b.x) >> 20], 1u);
        atomicAdd(&lh[keyOfU(b.y) >> 20], 1u);
        atomicAdd(&lh[keyOfU(b.z) >> 20], 1u);
        atomicAdd(&lh[keyOfU(b.w) >> 20], 1u);
    }
    if (i < PER / 4) {
        uint4 a = p[i];
        atomicAdd(&lh[keyOfU(a.x) >> 20], 1u);
        atomicAdd(&lh[keyOfU(a.y) >> 20], 1u);
        atomicAdd(&lh[keyOfU(a.z) >> 20], 1u);
        atomicAdd(&lh[keyOfU(a.w) >> 20], 1u);
    }
    __syncthreads();
    unsigned* dst = bh + ((size_t)n * HBLK + blockIdx.x) * HBINS;
    for (int b = threadIdx.x; b < HBINS; b += 256) dst[b] = lh[b];
}

// ---------- fused reduce + suffix-scan -> 12-bit threshold ------------------
__global__ __launch_bounds__(1024)
void k_sel(const unsigned* __restrict__ bh, unsigned* __restrict__ selT12) {
    int n = blockIdx.x, t = threadIdx.x;
    __shared__ unsigned L[1024];
    unsigned c0 = 0, c1 = 0, c2 = 0, c3 = 0;
    const unsigned* base = bh + (size_t)n * HBLK * HBINS + 4 * t;
    for (int blk = 0; blk < HBLK; ++blk) {
        uint4 v = *(const uint4*)(base + (size_t)blk * HBINS);
        c0 += v.x; c1 += v.y; c2 += v.z; c3 += v.w;
    }
    unsigned s3 = c3, s2 = c2 + s3, s1 = c1 + s2, s0 = c0 + s1;
    L[t] = s0;
    __syncthreads();
    for (int off = 1; off < 1024; off <<= 1) {
        unsigned v = L[t] + ((t + off < 1024) ? L[t + off] : 0u);
        __syncthreads(); L[t] = v; __syncthreads();
    }
    unsigned tail = (t < 1023) ? L[t + 1] : 0u;
    unsigned sf1 = s1 + tail, sf2 = s2 + tail, sf3 = s3 + tail, sf0 = s0 + tail;
    if (sf0 >= K_PRE && sf1 < K_PRE) selT12[n] = 4u * t + 0u;
    if (sf1 >= K_PRE && sf2 < K_PRE) selT12[n] = 4u * t + 1u;
    if (sf2 >= K_PRE && sf3 < K_PRE) selT12[n] = 4u * t + 2u;
    if (sf3 >= K_PRE && tail < K_PRE) selT12[n] = 4u * t + 3u;
}

// ---------- compact candidates into fixed per-block slices (NO global atomics)
__global__ __launch_bounds__(256)
void k_compact(const uint4* __restrict__ cls4, const unsigned* __restrict__ selT12,
               u64* __restrict__ cand) {
    int n = blockIdx.y;
    unsigned t12 = selT12[n];
    __shared__ unsigned cnt;
    if (threadIdx.x == 0) cnt = 0;
    __syncthreads();
    u64* slice = cand + (size_t)n * SORTN + (size_t)blockIdx.x * SLICE;
    const uint4* p = cls4 + (size_t)n * (PER / 4);
    int stride = gridDim.x * 256;
    for (int i4 = blockIdx.x * 256 + threadIdx.x; i4 < PER / 4; i4 += stride) {
        uint4 v = p[i4];
        unsigned k[4] = {keyOfU(v.x), keyOfU(v.y), keyOfU(v.z), keyOfU(v.w)};
        int i0 = i4 * 4;
        int a = i0 / HWSZ;                 // uniform across the 4 (HWSZ % 4 == 0)
        int r0 = i0 - a * HWSZ;
#pragma unroll
        for (int c = 0; c < 4; ++c) {
            if ((k[c] >> 20) >= t12) {
                unsigned pos = atomicAdd(&cnt, 1u);        // LDS atomic only
                if (pos < SLICE) {
                    unsigned idx = (unsigned)((r0 + c) * AN + a);
                    slice[pos] = ((u64)k[c] << 32) | (u64)(~idx);
                }
            }
        }
    }
    __syncthreads();
    unsigned c0 = cnt; if (c0 > SLICE) c0 = SLICE;
    for (unsigned t = c0 + threadIdx.x; t < SLICE; t += 256) slice[t] = 0ull;
}

// ---------- per-image: bitonic sort, decode top-2000, stable partition ------
__global__ __launch_bounds__(1024)
void k_sortdecode(const float* __restrict__ reg, const float* __restrict__ anchors,
                  const int* __restrict__ pih, const int* __restrict__ piw,
                  const u64* __restrict__ cand,
                  float* __restrict__ boxes_s, float* __restrict__ scores_s) {
    int n = blockIdx.x;
    int tid = threadIdx.x;
    __shared__ u64 sb[SORTN];               // 64 KB; scan buffers alias later
    for (int t = tid; t < SORTN; t += 1024)
        sb[t] = cand[(size_t)n * SORTN + t];
    __syncthreads();

    // bitonic sort descending (primary key desc, secondary ~idx desc = idx asc)
    for (int k = 2; k <= SORTN; k <<= 1) {
        for (int j = k >> 1; j > 0; j >>= 1) {
            for (int t = tid; t < SORTN / 2; t += 1024) {
                int i = ((t & ~(j - 1)) << 1) | (t & (j - 1));
                int p = i | j;
                bool desc = ((i & k) == 0);
                u64 a = sb[i], b = sb[p];
                bool sw = desc ? (a < b) : (a > b);
                if (sw) { sb[i] = b; sb[p] = a; }
            }
            __syncthreads();
        }
    }

    float fh = (float)(*pih);
    float fw = (float)(*piw);

    float bx[2][4]; float sc[2]; int pred[2]; int tt[2];
    tt[0] = tid; tt[1] = tid + 1024;
#pragma unroll
    for (int q = 0; q < 2; ++q) {
        int t = tt[q];
        pred[q] = 0; sc[q] = -1.0f;
        bx[q][0] = bx[q][1] = bx[q][2] = bx[q][3] = 0.f;
        if (t < K_PRE) {
            u64 e = sb[t];
            unsigned key = (unsigned)(e >> 32);
            unsigned idx = ~((unsigned)e);
            float v = valOf(key);
            float s = 1.0f / (1.0f + expf(-v));
            int a = (int)(idx % AN);
            int r = (int)(idx / AN);
            size_t base = ((size_t)(n * AN + a) * 4) * HWSZ + r;
            float dx = reg[base];
            float dy = reg[base + HWSZ];
            float dw = reg[base + 2 * (size_t)HWSZ];
            float dh = reg[base + 3 * (size_t)HWSZ];
            float4 an4 = ((const float4*)anchors)[idx];
            float wa = an4.z - an4.x, ha = an4.w - an4.y;
            float cxa = an4.x + 0.5f * wa, cya = an4.y + 0.5f * ha;
            dw = fminf(dw, BBOX_CLIP_F); dh = fminf(dh, BBOX_CLIP_F);
            float cx = dx * wa + cxa, cy = dy * ha + cya;
            float w = wa * expf(dw), h = ha * expf(dh);
            float x1 = cx - 0.5f * w, y1 = cy - 0.5f * h;
            float x2 = cx + 0.5f * w, y2 = cy + 0.5f * h;
            x1 = fminf(fmaxf(x1, 0.f), fw);
            y1 = fminf(fmaxf(y1, 0.f), fh);
            x2 = fminf(fmaxf(x2, 0.f), fw);
            y2 = fminf(fmaxf(y2, 0.f), fh);
            bool valid = ((x2 - x1) >= 1.0f) && ((y2 - y1) >= 1.0f);
            bx[q][0] = x1; bx[q][1] = y1; bx[q][2] = x2; bx[q][3] = y2;
            sc[q] = s; pred[q] = valid ? 1 : 0;
        }
    }
    __syncthreads();

    // stable partition valid-first via Hillis-Steele inclusive scan over 2048
    int* scanA = (int*)sb;
    int* scanB = scanA + 2048;
    scanA[tt[0]] = pred[0];
    scanA[tt[1]] = pred[1];
    __syncthreads();
    int* cur = scanA; int* nxt = scanB;
    for (int off = 1; off < 2048; off <<= 1) {
        int a0 = cur[tt[0]] + ((tt[0] >= off) ? cur[tt[0] - off] : 0);
        int a1 = cur[tt[1]] + ((tt[1] >= off) ? cur[tt[1] - off] : 0);
        __syncthreads();
        nxt[tt[0]] = a0; nxt[tt[1]] = a1;
        __syncthreads();
        int* tmp = cur; cur = nxt; nxt = tmp;
    }
    int V = cur[2047];

#pragma unroll
    for (int q = 0; q < 2; ++q) {
        int t = tt[q];
        if (t < K_PRE) {
            int incl = cur[t];
            int pos = pred[q] ? (incl - 1) : (V + (t - incl));
            float4 b4; b4.x = bx[q][0]; b4.y = bx[q][1]; b4.z = bx[q][2]; b4.w = bx[q][3];
            ((float4*)boxes_s)[(size_t)n * K_PRE + pos] = b4;
            scores_s[(size_t)n * K_PRE + pos] = pred[q] ? sc[q] : -1.0f;
        }
    }
}

// ---------- transposed IoU mask: maskT[n][rowblk][col] = incoming edges -----
// bit b of maskT[n][rb][c] = (IoU(row rb*64+b, col c) > th) && (row < col)
__global__ __launch_bounds__(256)
void k_maskT(const float* __restrict__ boxes_s, u64* __restrict__ maskT) {
    int n = blockIdx.y, cb = blockIdx.x;
    int lane = threadIdx.x & 63, w = threadIdx.x >> 6;
    __shared__ float4 rowbuf[4][64];
    int c = cb * 64 + lane;
    bool cok = c < K_PRE;
    float4 c4;
    if (cok) c4 = ((const float4*)boxes_s)[(size_t)n * K_PRE + c];
    else { c4.x = c4.y = c4.z = c4.w = 0.f; }
    float areaC = (c4.z - c4.x) * (c4.w - c4.y);

    for (int rb = w; rb < 32; rb += 4) {
        u64 bits = 0;
        if (rb <= cb) {
            int r = rb * 64 + lane;
            float4 r4;
            if (r < K_PRE) r4 = ((const float4*)boxes_s)[(size_t)n * K_PRE + r];
            else { r4.x = r4.y = r4.z = r4.w = 0.f; }
            rowbuf[w][lane] = r4;
            if (cok) {
                int bmax = c - rb * 64; if (bmax > 64) bmax = 64;
                for (int b = 0; b < bmax; ++b) {
                    float4 q = rowbuf[w][b];
                    float ix = fminf(c4.z, q.z) - fmaxf(c4.x, q.x); ix = fmaxf(ix, 0.f);
                    float iy = fminf(c4.w, q.w) - fmaxf(c4.y, q.y); iy = fmaxf(iy, 0.f);
                    float inter = ix * iy;
                    float areaR = (q.z - q.x) * (q.w - q.y);
                    float iou = inter / (areaR + areaC - inter);
                    if (iou > NMS_TH) bits |= (1ull << b);
                }
            }
        }
        maskT[((size_t)n * 32 + rb) * 2048 + c] = bits;
    }
}

// ---------- greedy NMS: ballot-fixpoint per 64-block, zero shuffle chains ---
__global__ __launch_bounds__(64)
void k_scanT(const u64* __restrict__ maskT, const float* __restrict__ boxes_s,
             const float* __restrict__ scores_s, float* __restrict__ out) {
    int n = blockIdx.x;
    int lane = threadIdx.x;       // 64 threads, single wave
    __shared__ float ls[2048];
    __shared__ u64 keptw[32];
    for (int i = lane; i < 2048; i += 64)
        ls[i] = (i < K_PRE) ? scores_s[(size_t)n * K_PRE + i] : -1.0f;
    if (lane < 32) keptw[lane] = 0ull;
    __syncthreads();

    const u64* mb = maskT + (size_t)n * 32 * 2048;
    int kept_total = 0;

    u64 wv[32];
#pragma unroll
    for (int rb = 0; rb < 32; ++rb) wv[rb] = mb[(size_t)rb * 2048 + lane];

    for (int f = 0; f < 32; ++f) {
        int c = f * 64 + lane;

        u64 wn[32];
        if (f < 31) {
            int cn = c + 64;
#pragma unroll
            for (int rb = 0; rb < 32; ++rb) wn[rb] = mb[(size_t)rb * 2048 + cn];
        }

        u64 hit = 0;
#pragma unroll
        for (int rb = 0; rb < 32; ++rb) hit |= (wv[rb] & keptw[rb]);
        bool ext = hit != 0ull;
        u64 diag = wv[f];

        bool v = (ls[c] >= 0.0f) && !ext;
        u64 kept = __ballot(v);
        while (true) {
            u64 nk = __ballot(v && ((diag & kept) == 0ull));
            if (nk == kept) break;
            kept = nk;
        }

        if ((kept >> lane) & 1ull) {
            int rank = kept_total + (int)__popcll(kept & ((1ull << lane) - 1ull));
            if (rank < K_POST) {
                float4 b4 = ((const float4*)boxes_s)[(size_t)n * K_PRE + c];
                ((float4*)out)[(size_t)n * K_POST + rank] = b4;
                out[(size_t)NB * K_POST * 4 + (size_t)n * K_POST + rank] = ls[c];
            }
        }
        kept_total += (int)__popcll(kept);
        if (lane == 0) keptw[f] = kept;
        __syncthreads();
        if (kept_total >= K_POST || f == 31) break;
#pragma unroll
        for (int rb = 0; rb < 32; ++rb) wv[rb] = wn[rb];
    }
}

extern "C" void kernel_launch(void* const* d_in, const int* in_sizes, int n_in,
                              void* d_out, int out_size, void* d_ws, size_t ws_size,
                              hipStream_t stream) {
    const float* cls     = (const float*)d_in[0];
    const float* reg     = (const float*)d_in[1];
    const float* anchors = (const float*)d_in[2];
    const int*   pih     = (const int*)d_in[3];
    const int*   piw     = (const int*)d_in[4];
    float* out = (float*)d_out;

    char* w = (char*)d_ws;
    // Region A [0, 4 MiB), time-multiplexed (each producer runs after the
    // previous consumer on the same stream):
    //   bh    (k_hist -> k_sel)            8*32*4096*4 = 4,194,304
    //   cand  (k_compact -> k_sortdecode)  8*8192*8    =   524,288
    //   maskT (k_maskT -> k_scanT)         8*32*2048*8 = 4,194,304
    unsigned* bh      = (unsigned*)(w + 0);
    u64*      cand    = (u64*)(w + 0);
    u64*      maskT   = (u64*)(w + 0);
    unsigned* selT12    = (unsigned*)(w + 4194304);    // 32 B
    float*    boxes_s   = (float*)(w + 4194560);       // 8*2000*4*4 = 256,000
    float*    scores_s  = (float*)(w + 4450560);       // 8*2000*4   =  64,000
    // total 4,514,560 bytes (< 4,694,656 proven available in R1)

    hipMemsetAsync(d_out, 0, (size_t)out_size * sizeof(float), stream);

    k_hist<<<dim3(HBLK, NB), 256, 0, stream>>>((const uint4*)cls, bh);
    k_sel<<<NB, 1024, 0, stream>>>(bh, selT12);
    k_compact<<<dim3(CBLK, NB), 256, 0, stream>>>((const uint4*)cls, selT12, cand);
    k_sortdecode<<<NB, 1024, 0, stream>>>(reg, anchors, pih, piw,
                                          cand, boxes_s, scores_s);
    k_maskT<<<dim3(32, NB), 256, 0, stream>>>(boxes_s, maskT);
    k_scanT<<<NB, 64, 0, stream>>>(maskT, boxes_s, scores_s, out);
    (void)in_sizes; (void)n_in; (void)ws_size;
}

// Round 5
// 186.105 us; speedup vs baseline: 5.1136x; 1.1584x over previous
//
#include <hip/hip_runtime.h>
#include <hip/hip_bf16.h>
#include <stdint.h>

typedef unsigned long long u64;

#define AN 15
#define HH 200
#define WW 320
#define HWSZ (HH*WW)          // 64000
#define PER (AN*HWSZ)         // 960000 anchors per image
#define NB 8
#define K_PRE 2000
#define K_POST 1000
#define SORTN 4096
#define HBINS 4096
#define HBLK 64               // hist blocks per image
#define CBLK 16               // compact blocks per image
#define SLICE (SORTN/CBLK)    // 256 candidate slots per compact block
#define NMS_TH 0.7f
#define BBOX_CLIP_F 4.135166556742356f   // log(1000/16)

__device__ __forceinline__ unsigned keyOfU(unsigned u) {
    return (u & 0x80000000u) ? ~u : (u | 0x80000000u);
}
__device__ __forceinline__ float valOf(unsigned k) {
    unsigned u = (k & 0x80000000u) ? (k ^ 0x80000000u) : ~k;
    return __uint_as_float(u);
}

// ---------- pass 1: per-block private 12-bit hist -> global atomic flush ----
__global__ __launch_bounds__(256)
void k_hist(const uint4* __restrict__ cls4, unsigned* __restrict__ gh) {
    int n = blockIdx.y;
    __shared__ unsigned lh[HBINS];
    for (int b = threadIdx.x; b < HBINS; b += 256) lh[b] = 0;
    __syncthreads();
    const uint4* p = cls4 + (size_t)n * (PER / 4);
    int stride = gridDim.x * 256;
    int i = blockIdx.x * 256 + threadIdx.x;
    for (; i + stride < PER / 4; i += 2 * stride) {
        uint4 a = p[i];
        uint4 b = p[i + stride];
        atomicAdd(&lh[keyOfU(a.x) >> 20], 1u);
        atomicAdd(&lh[keyOfU(a.y) >> 20], 1u);
        atomicAdd(&lh[keyOfU(a.z) >> 20], 1u);
        atomicAdd(&lh[keyOfU(a.w) >> 20], 1u);
        atomicAdd(&lh[keyOfU(b.x) >> 20], 1u);
        atomicAdd(&lh[keyOfU(b.y) >> 20], 1u);
        atomicAdd(&lh[keyOfU(b.z) >> 20], 1u);
        atomicAdd(&lh[keyOfU(b.w) >> 20], 1u);
    }
    if (i < PER / 4) {
        uint4 a = p[i];
        atomicAdd(&lh[keyOfU(a.x) >> 20], 1u);
        atomicAdd(&lh[keyOfU(a.y) >> 20], 1u);
        atomicAdd(&lh[keyOfU(a.z) >> 20], 1u);
        atomicAdd(&lh[keyOfU(a.w) >> 20], 1u);
    }
    __syncthreads();
    unsigned* dst = gh + (size_t)n * HBINS;
    for (int b = threadIdx.x; b < HBINS; b += 256) {
        unsigned v = lh[b];
        if (v) atomicAdd(&dst[b], v);      // fire-and-forget, no return needed
    }
}

// ---------- suffix-scan of per-image hist -> 12-bit threshold ---------------
__global__ __launch_bounds__(1024)
void k_sel(const unsigned* __restrict__ gh, unsigned* __restrict__ selT12) {
    int n = blockIdx.x, t = threadIdx.x;
    __shared__ unsigned L[1024];
    uint4 v = *(const uint4*)(gh + (size_t)n * HBINS + 4 * t);
    unsigned s3 = v.w, s2 = v.z + s3, s1 = v.y + s2, s0 = v.x + s1;
    L[t] = s0;
    __syncthreads();
    for (int off = 1; off < 1024; off <<= 1) {
        unsigned x = L[t] + ((t + off < 1024) ? L[t + off] : 0u);
        __syncthreads(); L[t] = x; __syncthreads();
    }
    unsigned tail = (t < 1023) ? L[t + 1] : 0u;
    unsigned sf0 = s0 + tail, sf1 = s1 + tail, sf2 = s2 + tail, sf3 = s3 + tail;
    if (sf0 >= K_PRE && sf1 < K_PRE) selT12[n] = 4u * t + 0u;
    if (sf1 >= K_PRE && sf2 < K_PRE) selT12[n] = 4u * t + 1u;
    if (sf2 >= K_PRE && sf3 < K_PRE) selT12[n] = 4u * t + 2u;
    if (sf3 >= K_PRE && tail < K_PRE) selT12[n] = 4u * t + 3u;
}

// ---------- compact candidates into fixed per-block slices (no glb atomics) -
__global__ __launch_bounds__(256)
void k_compact(const uint4* __restrict__ cls4, const unsigned* __restrict__ selT12,
               u64* __restrict__ cand) {
    int n = blockIdx.y;
    unsigned t12 = selT12[n];
    __shared__ unsigned cnt;
    if (threadIdx.x == 0) cnt = 0;
    __syncthreads();
    u64* slice = cand + (size_t)n * SORTN + (size_t)blockIdx.x * SLICE;
    const uint4* p = cls4 + (size_t)n * (PER / 4);
    int stride = gridDim.x * 256;
    for (int i4 = blockIdx.x * 256 + threadIdx.x; i4 < PER / 4; i4 += stride) {
        uint4 v = p[i4];
        unsigned k[4] = {keyOfU(v.x), keyOfU(v.y), keyOfU(v.z), keyOfU(v.w)};
        int i0 = i4 * 4;
        int a = i0 / HWSZ;                 // uniform across the 4 (HWSZ % 4 == 0)
        int r0 = i0 - a * HWSZ;
#pragma unroll
        for (int c = 0; c < 4; ++c) {
            if ((k[c] >> 20) >= t12) {
                unsigned pos = atomicAdd(&cnt, 1u);        // LDS atomic only
                if (pos < SLICE) {
                    unsigned idx = (unsigned)((r0 + c) * AN + a);
                    slice[pos] = ((u64)k[c] << 32) | (u64)(~idx);
                }
            }
        }
    }
    __syncthreads();
    unsigned c0 = cnt; if (c0 > SLICE) c0 = SLICE;
    for (unsigned t = c0 + threadIdx.x; t < SLICE; t += 256) slice[t] = 0ull;
}

// ---------- per-image: register-hybrid bitonic sort + decode + partition ----
// 512 threads x 8 u64 elements. j<=4 phases in registers, j>=8 in LDS.
__global__ __launch_bounds__(512)
void k_sortdecode(const float* __restrict__ reg, const float* __restrict__ anchors,
                  const int* __restrict__ pih, const int* __restrict__ piw,
                  const u64* __restrict__ cand,
                  float* __restrict__ boxes_s, float* __restrict__ scores_s) {
    int n = blockIdx.x;
    int tid = threadIdx.x;
    __shared__ u64 sb[SORTN];               // 32 KB
    u64 r[8];

#define CE(a_, b_, d_) { bool sw_ = (d_) ? (r[a_] < r[b_]) : (r[a_] > r[b_]); \
                         if (sw_) { u64 t_ = r[a_]; r[a_] = r[b_]; r[b_] = t_; } }

    {   // load own 8 elements, run k=2 and k=4 levels fully in registers
        const u64* src = cand + (size_t)n * SORTN + 8 * tid;
#pragma unroll
        for (int e = 0; e < 8; ++e) r[e] = src[e];
        // k=2, j=1  (dir = ((e&2)==0))
        CE(0, 1, true)  CE(2, 3, false) CE(4, 5, true)  CE(6, 7, false)
        // k=4, j=2  (dir = ((e&4)==0))
        CE(0, 2, true)  CE(1, 3, true)  CE(4, 6, false) CE(5, 7, false)
        // k=4, j=1
        CE(0, 1, true)  CE(2, 3, true)  CE(4, 5, false) CE(6, 7, false)
#pragma unroll
        for (int e = 0; e < 8; ++e) sb[8 * tid + e] = r[e];
        __syncthreads();
    }

    for (int k = 8; k <= SORTN; k <<= 1) {
        for (int j = k >> 1; j >= 8; j >>= 1) {
#pragma unroll
            for (int s = 0; s < 4; ++s) {
                int c = tid + s * 512;
                int i = ((c & ~(j - 1)) << 1) | (c & (j - 1));
                int p = i | j;
                bool dir = (i & k) == 0;
                u64 a = sb[i], b = sb[p];
                bool sw = dir ? (a < b) : (a > b);
                if (sw) { sb[i] = b; sb[p] = a; }
            }
            __syncthreads();
        }
        {   // register pass: j = 4, 2, 1 (dir uniform per thread for k>=8)
            int base = 8 * tid;
            bool d = (base & k) == 0;
#pragma unroll
            for (int e = 0; e < 8; ++e) r[e] = sb[base + e];
            CE(0, 4, d) CE(1, 5, d) CE(2, 6, d) CE(3, 7, d)   // j=4
            CE(0, 2, d) CE(1, 3, d) CE(4, 6, d) CE(5, 7, d)   // j=2
            CE(0, 1, d) CE(2, 3, d) CE(4, 5, d) CE(6, 7, d)   // j=1
#pragma unroll
            for (int e = 0; e < 8; ++e) sb[base + e] = r[e];
            __syncthreads();
        }
    }
#undef CE

    float fh = (float)(*pih);
    float fw = (float)(*piw);

    // decode entries tt[q] = tid + 512q  (q=0..3, covers 0..2047)
    float bx[4][4]; float sc[4]; int pred[4];
#pragma unroll
    for (int q = 0; q < 4; ++q) {
        int t = tid + 512 * q;
        pred[q] = 0; sc[q] = -1.0f;
        bx[q][0] = bx[q][1] = bx[q][2] = bx[q][3] = 0.f;
        if (t < K_PRE) {
            u64 e = sb[t];
            unsigned key = (unsigned)(e >> 32);
            unsigned idx = ~((unsigned)e);
            float v = valOf(key);
            float s = 1.0f / (1.0f + expf(-v));
            int a = (int)(idx % AN);
            int rr = (int)(idx / AN);
            size_t base = ((size_t)(n * AN + a) * 4) * HWSZ + rr;
            float dx = reg[base];
            float dy = reg[base + HWSZ];
            float dw = reg[base + 2 * (size_t)HWSZ];
            float dh = reg[base + 3 * (size_t)HWSZ];
            float4 an4 = ((const float4*)anchors)[idx];
            float wa = an4.z - an4.x, ha = an4.w - an4.y;
            float cxa = an4.x + 0.5f * wa, cya = an4.y + 0.5f * ha;
            dw = fminf(dw, BBOX_CLIP_F); dh = fminf(dh, BBOX_CLIP_F);
            float cx = dx * wa + cxa, cy = dy * ha + cya;
            float w = wa * expf(dw), h = ha * expf(dh);
            float x1 = cx - 0.5f * w, y1 = cy - 0.5f * h;
            float x2 = cx + 0.5f * w, y2 = cy + 0.5f * h;
            x1 = fminf(fmaxf(x1, 0.f), fw);
            y1 = fminf(fmaxf(y1, 0.f), fh);
            x2 = fminf(fmaxf(x2, 0.f), fw);
            y2 = fminf(fmaxf(y2, 0.f), fh);
            bool valid = ((x2 - x1) >= 1.0f) && ((y2 - y1) >= 1.0f);
            bx[q][0] = x1; bx[q][1] = y1; bx[q][2] = x2; bx[q][3] = y2;
            sc[q] = s; pred[q] = valid ? 1 : 0;
        }
    }
    __syncthreads();

    // stable valid-first partition via per-wave ballots (2048 entries)
    __shared__ u64 ww[32];
    __shared__ int wpfx[33];
    int lane = tid & 63, wid = tid >> 6;     // 8 waves
#pragma unroll
    for (int q = 0; q < 4; ++q) {
        u64 bal = __ballot(pred[q] != 0);
        if (lane == 0) ww[wid + 8 * q] = bal;
    }
    __syncthreads();
    if (tid == 0) {
        int s = 0;
#pragma unroll
        for (int w2 = 0; w2 < 32; ++w2) { wpfx[w2] = s; s += (int)__popcll(ww[w2]); }
        wpfx[32] = s;
    }
    __syncthreads();
    int V = wpfx[32];

#pragma unroll
    for (int q = 0; q < 4; ++q) {
        int t = tid + 512 * q;
        if (t < K_PRE) {
            int wi = t >> 6;
            int before = wpfx[wi] + (int)__popcll(ww[wi] & ((1ull << (unsigned)lane) - 1ull));
            int pos = pred[q] ? before : (V + (t - before));
            float4 b4; b4.x = bx[q][0]; b4.y = bx[q][1]; b4.z = bx[q][2]; b4.w = bx[q][3];
            ((float4*)boxes_s)[(size_t)n * K_PRE + pos] = b4;
            scores_s[(size_t)n * K_PRE + pos] = pred[q] ? sc[q] : -1.0f;
        }
    }
}

// ---------- transposed IoU mask: maskT[n][rowblk][col] = incoming edges -----
__global__ __launch_bounds__(256)
void k_maskT(const float* __restrict__ boxes_s, u64* __restrict__ maskT) {
    int n = blockIdx.y, cb = blockIdx.x;
    int lane = threadIdx.x & 63, w = threadIdx.x >> 6;
    __shared__ float4 rowbuf[4][64];
    int c = cb * 64 + lane;
    bool cok = c < K_PRE;
    float4 c4;
    if (cok) c4 = ((const float4*)boxes_s)[(size_t)n * K_PRE + c];
    else { c4.x = c4.y = c4.z = c4.w = 0.f; }
    float areaC = (c4.z - c4.x) * (c4.w - c4.y);

    for (int rb = w; rb < 32; rb += 4) {
        u64 bits = 0;
        if (rb <= cb) {
            int r = rb * 64 + lane;
            float4 r4;
            if (r < K_PRE) r4 = ((const float4*)boxes_s)[(size_t)n * K_PRE + r];
            else { r4.x = r4.y = r4.z = r4.w = 0.f; }
            rowbuf[w][lane] = r4;
            if (cok) {
                int bmax = c - rb * 64; if (bmax > 64) bmax = 64;
                for (int b = 0; b < bmax; ++b) {
                    float4 q = rowbuf[w][b];
                    float ix = fminf(c4.z, q.z) - fmaxf(c4.x, q.x); ix = fmaxf(ix, 0.f);
                    float iy = fminf(c4.w, q.w) - fmaxf(c4.y, q.y); iy = fmaxf(iy, 0.f);
                    float inter = ix * iy;
                    float areaR = (q.z - q.x) * (q.w - q.y);
                    float iou = inter / (areaR + areaC - inter);
                    if (iou > NMS_TH) bits |= (1ull << b);
                }
            }
        }
        maskT[((size_t)n * 32 + rb) * 2048 + c] = bits;
    }
}

// ---------- greedy NMS: ballot-fixpoint per 64-block, zero shuffle chains ---
__global__ __launch_bounds__(64)
void k_scanT(const u64* __restrict__ maskT, const float* __restrict__ boxes_s,
             const float* __restrict__ scores_s, float* __restrict__ out) {
    int n = blockIdx.x;
    int lane = threadIdx.x;       // 64 threads, single wave
    __shared__ float ls[2048];
    __shared__ u64 keptw[32];
    for (int i = lane; i < 2048; i += 64)
        ls[i] = (i < K_PRE) ? scores_s[(size_t)n * K_PRE + i] : -1.0f;
    if (lane < 32) keptw[lane] = 0ull;
    __syncthreads();

    const u64* mb = maskT + (size_t)n * 32 * 2048;
    int kept_total = 0;

    u64 wv[32];
#pragma unroll
    for (int rb = 0; rb < 32; ++rb) wv[rb] = mb[(size_t)rb * 2048 + lane];

    for (int f = 0; f < 32; ++f) {
        int c = f * 64 + lane;

        u64 wn[32];
        if (f < 31) {
            int cn = c + 64;
#pragma unroll
            for (int rb = 0; rb < 32; ++rb) wn[rb] = mb[(size_t)rb * 2048 + cn];
        }

        u64 hit = 0;
#pragma unroll
        for (int rb = 0; rb < 32; ++rb) hit |= (wv[rb] & keptw[rb]);
        bool ext = hit != 0ull;
        u64 diag = wv[f];

        bool v = (ls[c] >= 0.0f) && !ext;
        u64 kept = __ballot(v);
        while (true) {
            u64 nk = __ballot(v && ((diag & kept) == 0ull));
            if (nk == kept) break;
            kept = nk;
        }

        if ((kept >> lane) & 1ull) {
            int rank = kept_total + (int)__popcll(kept & ((1ull << lane) - 1ull));
            if (rank < K_POST) {
                float4 b4 = ((const float4*)boxes_s)[(size_t)n * K_PRE + c];
                ((float4*)out)[(size_t)n * K_POST + rank] = b4;
                out[(size_t)NB * K_POST * 4 + (size_t)n * K_POST + rank] = ls[c];
            }
        }
        kept_total += (int)__popcll(kept);
        if (lane == 0) keptw[f] = kept;
        __syncthreads();
        if (kept_total >= K_POST || f == 31) break;
#pragma unroll
        for (int rb = 0; rb < 32; ++rb) wv[rb] = wn[rb];
    }
}

extern "C" void kernel_launch(void* const* d_in, const int* in_sizes, int n_in,
                              void* d_out, int out_size, void* d_ws, size_t ws_size,
                              hipStream_t stream) {
    const float* cls     = (const float*)d_in[0];
    const float* reg     = (const float*)d_in[1];
    const float* anchors = (const float*)d_in[2];
    const int*   pih     = (const int*)d_in[3];
    const int*   piw     = (const int*)d_in[4];
    float* out = (float*)d_out;

    char* w = (char*)d_ws;
    // Region A [0, 4 MiB), time-multiplexed (strict stream order):
    //   gh    (memset -> k_hist -> k_sel)      8*4096*4  =   131,072
    //   cand  (k_compact -> k_sortdecode)      8*4096*8  =   262,144
    //   maskT (k_maskT -> k_scanT)             8*32*2048*8 = 4,194,304
    unsigned* gh      = (unsigned*)(w + 0);
    u64*      cand    = (u64*)(w + 0);
    u64*      maskT   = (u64*)(w + 0);
    unsigned* selT12    = (unsigned*)(w + 4194304);    // 32 B
    float*    boxes_s   = (float*)(w + 4194560);       // 8*2000*4*4 = 256,000
    float*    scores_s  = (float*)(w + 4450560);       // 8*2000*4   =  64,000
    // total 4,514,560 bytes

    hipMemsetAsync(gh, 0, (size_t)NB * HBINS * sizeof(unsigned), stream);
    hipMemsetAsync(d_out, 0, (size_t)out_size * sizeof(float), stream);

    k_hist<<<dim3(HBLK, NB), 256, 0, stream>>>((const uint4*)cls, gh);
    k_sel<<<NB, 1024, 0, stream>>>(gh, selT12);
    k_compact<<<dim3(CBLK, NB), 256, 0, stream>>>((const uint4*)cls, selT12, cand);
    k_sortdecode<<<NB, 512, 0, stream>>>(reg, anchors, pih, piw,
                                         cand, boxes_s, scores_s);
    k_maskT<<<dim3(32, NB), 256, 0, stream>>>(boxes_s, maskT);
    k_scanT<<<NB, 64, 0, stream>>>(maskT, boxes_s, scores_s, out);
    (void)in_sizes; (void)n_in; (void)ws_size;
}

// Round 6
// 185.245 us; speedup vs baseline: 5.1373x; 1.0046x over previous
//
#include <hip/hip_runtime.h>
#include <hip/hip_bf16.h>
#include <stdint.h>

typedef unsigned long long u64;

#define AN 15
#define HH 200
#define WW 320
#define HWSZ (HH*WW)          // 64000
#define PER (AN*HWSZ)         // 960000 anchors per image
#define NB 8
#define K_PRE 2000
#define K_POST 1000
#define SORTN 4096
#define HBINS 4096
#define HBLK 64               // hist blocks per image
#define CBLK 16               // compact blocks per image
#define SLICE (SORTN/CBLK)    // 256 candidate slots per compact block
#define NMS_TH 0.7f
#define BBOX_CLIP_F 4.135166556742356f   // log(1000/16)

__device__ __forceinline__ unsigned keyOfU(unsigned u) {
    return (u & 0x80000000u) ? ~u : (u | 0x80000000u);
}
__device__ __forceinline__ float valOf(unsigned k) {
    unsigned u = (k & 0x80000000u) ? (k ^ 0x80000000u) : ~k;
    return __uint_as_float(u);
}

// ---------- zero-init gh (replaces fillBufferAligned node) ------------------
__global__ __launch_bounds__(256)
void z_init(uint4* __restrict__ gh4) {
    gh4[blockIdx.x * 256 + threadIdx.x] = make_uint4(0, 0, 0, 0);
}

// ---------- pass 1: dual private 12-bit hist -> global atomic flush ---------
__global__ __launch_bounds__(256)
void k_hist(const uint4* __restrict__ cls4, unsigned* __restrict__ gh) {
    int n = blockIdx.y;
    __shared__ unsigned lh[2][HBINS];          // 32 KB, even/odd thread copies
    for (int b = threadIdx.x; b < HBINS; b += 256) { lh[0][b] = 0; lh[1][b] = 0; }
    __syncthreads();
    unsigned* myh = lh[threadIdx.x & 1];
    const uint4* p = cls4 + (size_t)n * (PER / 4);
    int stride = gridDim.x * 256;
    int i = blockIdx.x * 256 + threadIdx.x;
    for (; i + stride < PER / 4; i += 2 * stride) {
        uint4 a = p[i];
        uint4 b = p[i + stride];
        atomicAdd(&myh[keyOfU(a.x) >> 20], 1u);
        atomicAdd(&myh[keyOfU(a.y) >> 20], 1u);
        atomicAdd(&myh[keyOfU(a.z) >> 20], 1u);
        atomicAdd(&myh[keyOfU(a.w) >> 20], 1u);
        atomicAdd(&myh[keyOfU(b.x) >> 20], 1u);
        atomicAdd(&myh[keyOfU(b.y) >> 20], 1u);
        atomicAdd(&myh[keyOfU(b.z) >> 20], 1u);
        atomicAdd(&myh[keyOfU(b.w) >> 20], 1u);
    }
    if (i < PER / 4) {
        uint4 a = p[i];
        atomicAdd(&myh[keyOfU(a.x) >> 20], 1u);
        atomicAdd(&myh[keyOfU(a.y) >> 20], 1u);
        atomicAdd(&myh[keyOfU(a.z) >> 20], 1u);
        atomicAdd(&myh[keyOfU(a.w) >> 20], 1u);
    }
    __syncthreads();
    unsigned* dst = gh + (size_t)n * HBINS;
    for (int b = threadIdx.x; b < HBINS; b += 256) {
        unsigned v = lh[0][b] + lh[1][b];
        if (v) atomicAdd(&dst[b], v);      // fire-and-forget, no return needed
    }
}

// ---------- suffix-scan of per-image hist -> 12-bit threshold ---------------
__global__ __launch_bounds__(1024)
void k_sel(const unsigned* __restrict__ gh, unsigned* __restrict__ selT12) {
    int n = blockIdx.x, t = threadIdx.x;
    __shared__ unsigned L[1024];
    uint4 v = *(const uint4*)(gh + (size_t)n * HBINS + 4 * t);
    unsigned s3 = v.w, s2 = v.z + s3, s1 = v.y + s2, s0 = v.x + s1;
    L[t] = s0;
    __syncthreads();
    for (int off = 1; off < 1024; off <<= 1) {
        unsigned x = L[t] + ((t + off < 1024) ? L[t + off] : 0u);
        __syncthreads(); L[t] = x; __syncthreads();
    }
    unsigned tail = (t < 1023) ? L[t + 1] : 0u;
    unsigned sf0 = s0 + tail, sf1 = s1 + tail, sf2 = s2 + tail, sf3 = s3 + tail;
    if (sf0 >= K_PRE && sf1 < K_PRE) selT12[n] = 4u * t + 0u;
    if (sf1 >= K_PRE && sf2 < K_PRE) selT12[n] = 4u * t + 1u;
    if (sf2 >= K_PRE && sf3 < K_PRE) selT12[n] = 4u * t + 2u;
    if (sf3 >= K_PRE && tail < K_PRE) selT12[n] = 4u * t + 3u;
}

// ---------- compact candidates into fixed per-block slices (no glb atomics) -
__global__ __launch_bounds__(256)
void k_compact(const uint4* __restrict__ cls4, const unsigned* __restrict__ selT12,
               u64* __restrict__ cand) {
    int n = blockIdx.y;
    unsigned t12 = selT12[n];
    __shared__ unsigned cnt;
    if (threadIdx.x == 0) cnt = 0;
    __syncthreads();
    u64* slice = cand + (size_t)n * SORTN + (size_t)blockIdx.x * SLICE;
    const uint4* p = cls4 + (size_t)n * (PER / 4);
    int stride = gridDim.x * 256;
    for (int i4 = blockIdx.x * 256 + threadIdx.x; i4 < PER / 4; i4 += stride) {
        uint4 v = p[i4];
        unsigned k[4] = {keyOfU(v.x), keyOfU(v.y), keyOfU(v.z), keyOfU(v.w)};
        int i0 = i4 * 4;
        int a = i0 / HWSZ;                 // uniform across the 4 (HWSZ % 4 == 0)
        int r0 = i0 - a * HWSZ;
#pragma unroll
        for (int c = 0; c < 4; ++c) {
            if ((k[c] >> 20) >= t12) {
                unsigned pos = atomicAdd(&cnt, 1u);        // LDS atomic only
                if (pos < SLICE) {
                    unsigned idx = (unsigned)((r0 + c) * AN + a);
                    slice[pos] = ((u64)k[c] << 32) | (u64)(~idx);
                }
            }
        }
    }
    __syncthreads();
    unsigned c0 = cnt; if (c0 > SLICE) c0 = SLICE;
    for (unsigned t = c0 + threadIdx.x; t < SLICE; t += 256) slice[t] = 0ull;
}

// ---------- per-image: register-hybrid bitonic sort + decode + partition ----
__global__ __launch_bounds__(512)
void k_sortdecode(const float* __restrict__ reg, const float* __restrict__ anchors,
                  const int* __restrict__ pih, const int* __restrict__ piw,
                  const u64* __restrict__ cand,
                  float* __restrict__ boxes_s, float* __restrict__ scores_s) {
    int n = blockIdx.x;
    int tid = threadIdx.x;
    __shared__ u64 sb[SORTN];               // 32 KB
    u64 r[8];

#define CE(a_, b_, d_) { bool sw_ = (d_) ? (r[a_] < r[b_]) : (r[a_] > r[b_]); \
                         if (sw_) { u64 t_ = r[a_]; r[a_] = r[b_]; r[b_] = t_; } }

    {   // load own 8 elements, run k=2 and k=4 levels fully in registers
        const u64* src = cand + (size_t)n * SORTN + 8 * tid;
#pragma unroll
        for (int e = 0; e < 8; ++e) r[e] = src[e];
        CE(0, 1, true)  CE(2, 3, false) CE(4, 5, true)  CE(6, 7, false)
        CE(0, 2, true)  CE(1, 3, true)  CE(4, 6, false) CE(5, 7, false)
        CE(0, 1, true)  CE(2, 3, true)  CE(4, 5, false) CE(6, 7, false)
#pragma unroll
        for (int e = 0; e < 8; ++e) sb[8 * tid + e] = r[e];
        __syncthreads();
    }

    for (int k = 8; k <= SORTN; k <<= 1) {
        for (int j = k >> 1; j >= 8; j >>= 1) {
#pragma unroll
            for (int s = 0; s < 4; ++s) {
                int c = tid + s * 512;
                int i = ((c & ~(j - 1)) << 1) | (c & (j - 1));
                int p = i | j;
                bool dir = (i & k) == 0;
                u64 a = sb[i], b = sb[p];
                bool sw = dir ? (a < b) : (a > b);
                if (sw) { sb[i] = b; sb[p] = a; }
            }
            __syncthreads();
        }
        {   // register pass: j = 4, 2, 1 (dir uniform per thread for k>=8)
            int base = 8 * tid;
            bool d = (base & k) == 0;
#pragma unroll
            for (int e = 0; e < 8; ++e) r[e] = sb[base + e];
            CE(0, 4, d) CE(1, 5, d) CE(2, 6, d) CE(3, 7, d)
            CE(0, 2, d) CE(1, 3, d) CE(4, 6, d) CE(5, 7, d)
            CE(0, 1, d) CE(2, 3, d) CE(4, 5, d) CE(6, 7, d)
#pragma unroll
            for (int e = 0; e < 8; ++e) sb[base + e] = r[e];
            __syncthreads();
        }
    }
#undef CE

    float fh = (float)(*pih);
    float fw = (float)(*piw);

    float bx[4][4]; float sc[4]; int pred[4];
#pragma unroll
    for (int q = 0; q < 4; ++q) {
        int t = tid + 512 * q;
        pred[q] = 0; sc[q] = -1.0f;
        bx[q][0] = bx[q][1] = bx[q][2] = bx[q][3] = 0.f;
        if (t < K_PRE) {
            u64 e = sb[t];
            unsigned key = (unsigned)(e >> 32);
            unsigned idx = ~((unsigned)e);
            float v = valOf(key);
            float s = 1.0f / (1.0f + expf(-v));
            int a = (int)(idx % AN);
            int rr = (int)(idx / AN);
            size_t base = ((size_t)(n * AN + a) * 4) * HWSZ + rr;
            float dx = reg[base];
            float dy = reg[base + HWSZ];
            float dw = reg[base + 2 * (size_t)HWSZ];
            float dh = reg[base + 3 * (size_t)HWSZ];
            float4 an4 = ((const float4*)anchors)[idx];
            float wa = an4.z - an4.x, ha = an4.w - an4.y;
            float cxa = an4.x + 0.5f * wa, cya = an4.y + 0.5f * ha;
            dw = fminf(dw, BBOX_CLIP_F); dh = fminf(dh, BBOX_CLIP_F);
            float cx = dx * wa + cxa, cy = dy * ha + cya;
            float w = wa * expf(dw), h = ha * expf(dh);
            float x1 = cx - 0.5f * w, y1 = cy - 0.5f * h;
            float x2 = cx + 0.5f * w, y2 = cy + 0.5f * h;
            x1 = fminf(fmaxf(x1, 0.f), fw);
            y1 = fminf(fmaxf(y1, 0.f), fh);
            x2 = fminf(fmaxf(x2, 0.f), fw);
            y2 = fminf(fmaxf(y2, 0.f), fh);
            bool valid = ((x2 - x1) >= 1.0f) && ((y2 - y1) >= 1.0f);
            bx[q][0] = x1; bx[q][1] = y1; bx[q][2] = x2; bx[q][3] = y2;
            sc[q] = s; pred[q] = valid ? 1 : 0;
        }
    }
    __syncthreads();

    // stable valid-first partition via per-wave ballots (2048 entries)
    __shared__ u64 ww[32];
    __shared__ int wpfx[33];
    int lane = tid & 63, wid = tid >> 6;     // 8 waves
#pragma unroll
    for (int q = 0; q < 4; ++q) {
        u64 bal = __ballot(pred[q] != 0);
        if (lane == 0) ww[wid + 8 * q] = bal;
    }
    __syncthreads();
    if (tid == 0) {
        int s = 0;
#pragma unroll
        for (int w2 = 0; w2 < 32; ++w2) { wpfx[w2] = s; s += (int)__popcll(ww[w2]); }
        wpfx[32] = s;
    }
    __syncthreads();
    int V = wpfx[32];

#pragma unroll
    for (int q = 0; q < 4; ++q) {
        int t = tid + 512 * q;
        if (t < K_PRE) {
            int wi = t >> 6;
            int before = wpfx[wi] + (int)__popcll(ww[wi] & ((1ull << (unsigned)lane) - 1ull));
            int pos = pred[q] ? before : (V + (t - before));
            float4 b4; b4.x = bx[q][0]; b4.y = bx[q][1]; b4.z = bx[q][2]; b4.w = bx[q][3];
            ((float4*)boxes_s)[(size_t)n * K_PRE + pos] = b4;
            scores_s[(size_t)n * K_PRE + pos] = pred[q] ? sc[q] : -1.0f;
        }
    }
}

// ---------- transposed IoU mask: maskT[n][rowblk][col] = incoming edges -----
__global__ __launch_bounds__(256)
void k_maskT(const float* __restrict__ boxes_s, u64* __restrict__ maskT) {
    int n = blockIdx.y, cb = blockIdx.x;
    int lane = threadIdx.x & 63, w = threadIdx.x >> 6;
    __shared__ float4 rowbuf[4][64];
    int c = cb * 64 + lane;
    bool cok = c < K_PRE;
    float4 c4;
    if (cok) c4 = ((const float4*)boxes_s)[(size_t)n * K_PRE + c];
    else { c4.x = c4.y = c4.z = c4.w = 0.f; }
    float areaC = (c4.z - c4.x) * (c4.w - c4.y);

    for (int rb = w; rb < 32; rb += 4) {
        u64 bits = 0;
        if (rb <= cb) {
            int r = rb * 64 + lane;
            float4 r4;
            if (r < K_PRE) r4 = ((const float4*)boxes_s)[(size_t)n * K_PRE + r];
            else { r4.x = r4.y = r4.z = r4.w = 0.f; }
            rowbuf[w][lane] = r4;
            if (cok) {
                int bmax = c - rb * 64; if (bmax > 64) bmax = 64;
                for (int b = 0; b < bmax; ++b) {
                    float4 q = rowbuf[w][b];
                    float ix = fminf(c4.z, q.z) - fmaxf(c4.x, q.x); ix = fmaxf(ix, 0.f);
                    float iy = fminf(c4.w, q.w) - fmaxf(c4.y, q.y); iy = fmaxf(iy, 0.f);
                    float inter = ix * iy;
                    float areaR = (q.z - q.x) * (q.w - q.y);
                    float iou = inter / (areaR + areaC - inter);
                    if (iou > NMS_TH) bits |= (1ull << b);
                }
            }
        }
        maskT[((size_t)n * 32 + rb) * 2048 + c] = bits;
    }
}

// ---------- greedy NMS: ballot-fixpoint per 64-block + output (incl. tail 0) -
__global__ __launch_bounds__(64)
void k_scanT(const u64* __restrict__ maskT, const float* __restrict__ boxes_s,
             const float* __restrict__ scores_s, float* __restrict__ out) {
    int n = blockIdx.x;
    int lane = threadIdx.x;       // 64 threads, single wave
    __shared__ float ls[2048];
    __shared__ u64 keptw[32];
    for (int i = lane; i < 2048; i += 64)
        ls[i] = (i < K_PRE) ? scores_s[(size_t)n * K_PRE + i] : -1.0f;
    if (lane < 32) keptw[lane] = 0ull;
    __syncthreads();

    const u64* mb = maskT + (size_t)n * 32 * 2048;
    int kept_total = 0;

    u64 wv[32];
#pragma unroll
    for (int rb = 0; rb < 32; ++rb) wv[rb] = mb[(size_t)rb * 2048 + lane];

    for (int f = 0; f < 32; ++f) {
        int c = f * 64 + lane;

        u64 wn[32];
        if (f < 31) {
            int cn = c + 64;
#pragma unroll
            for (int rb = 0; rb < 32; ++rb) wn[rb] = mb[(size_t)rb * 2048 + cn];
        }

        u64 hit = 0;
#pragma unroll
        for (int rb = 0; rb < 32; ++rb) hit |= (wv[rb] & keptw[rb]);
        bool ext = hit != 0ull;
        u64 diag = wv[f];

        bool v = (ls[c] >= 0.0f) && !ext;
        u64 kept = __ballot(v);
        while (true) {
            u64 nk = __ballot(v && ((diag & kept) == 0ull));
            if (nk == kept) break;
            kept = nk;
        }

        if ((kept >> lane) & 1ull) {
            int rank = kept_total + (int)__popcll(kept & ((1ull << lane) - 1ull));
            if (rank < K_POST) {
                float4 b4 = ((const float4*)boxes_s)[(size_t)n * K_PRE + c];
                ((float4*)out)[(size_t)n * K_POST + rank] = b4;
                out[(size_t)NB * K_POST * 4 + (size_t)n * K_POST + rank] = ls[c];
            }
        }
        kept_total += (int)__popcll(kept);
        if (lane == 0) keptw[f] = kept;
        __syncthreads();
        if (kept_total >= K_POST || f == 31) break;
#pragma unroll
        for (int rb = 0; rb < 32; ++rb) wv[rb] = wn[rb];
    }

    // zero output tail (replaces the d_out memset; makes every byte written)
    int start = (kept_total < K_POST) ? kept_total : K_POST;
    float4 z4; z4.x = z4.y = z4.z = z4.w = 0.f;
    for (int rk = start + lane; rk < K_POST; rk += 64) {
        ((float4*)out)[(size_t)n * K_POST + rk] = z4;
        out[(size_t)NB * K_POST * 4 + (size_t)n * K_POST + rk] = 0.f;
    }
}

extern "C" void kernel_launch(void* const* d_in, const int* in_sizes, int n_in,
                              void* d_out, int out_size, void* d_ws, size_t ws_size,
                              hipStream_t stream) {
    const float* cls     = (const float*)d_in[0];
    const float* reg     = (const float*)d_in[1];
    const float* anchors = (const float*)d_in[2];
    const int*   pih     = (const int*)d_in[3];
    const int*   piw     = (const int*)d_in[4];
    float* out = (float*)d_out;

    char* w = (char*)d_ws;
    // Region A [0, 4 MiB), time-multiplexed (strict stream order):
    //   gh    (z_init -> k_hist -> k_sel)      8*4096*4  =   131,072
    //   cand  (k_compact -> k_sortdecode)      8*4096*8  =   262,144
    //   maskT (k_maskT -> k_scanT)             8*32*2048*8 = 4,194,304
    unsigned* gh      = (unsigned*)(w + 0);
    u64*      cand    = (u64*)(w + 0);
    u64*      maskT   = (u64*)(w + 0);
    unsigned* selT12    = (unsigned*)(w + 4194304);    // 32 B
    float*    boxes_s   = (float*)(w + 4194560);       // 8*2000*4*4 = 256,000
    float*    scores_s  = (float*)(w + 4450560);       // 8*2000*4   =  64,000
    // total 4,514,560 bytes

    z_init<<<(NB * HBINS * 4) / 4096, 256, 0, stream>>>((uint4*)gh);
    k_hist<<<dim3(HBLK, NB), 256, 0, stream>>>((const uint4*)cls, gh);
    k_sel<<<NB, 1024, 0, stream>>>(gh, selT12);
    k_compact<<<dim3(CBLK, NB), 256, 0, stream>>>((const uint4*)cls, selT12, cand);
    k_sortdecode<<<NB, 512, 0, stream>>>(reg, anchors, pih, piw,
                                         cand, boxes_s, scores_s);
    k_maskT<<<dim3(32, NB), 256, 0, stream>>>(boxes_s, maskT);
    k_scanT<<<NB, 64, 0, stream>>>(maskT, boxes_s, scores_s, out);
    (void)in_sizes; (void)n_in; (void)ws_size;
}